// Round 1
// 285.643 us; speedup vs baseline: 1.0398x; 1.0398x over previous
//
#include <hip/hip_runtime.h>

// Laplacian pyramid loss, 3 levels, B*C = 48 channels of 512x512 f32.
// R9 restructure: gauss-downsample factored into 3 small memory-bound
// down_kernel launches; ALL three loss levels merged into one balanced
// launch (grid 395x48) that reads its down window from global. Loss kernel
// drops s_cur/s_hb/shfl-gauss/phase-C/phase-W -> LDS 31.7KB -> 24.6KB
// (5 -> 6 blocks/CU). Phases D/E/F + edge geometry kept verbatim from the
// verified R8 kernel; down values computed with identical FP ordering.

#define NCH 48

__device__ __forceinline__ int refl(int p, int n) {
  return p < 0 ? -p : (p >= n ? 2 * n - 2 - p : p);
}

// ---------------- down kernel: dst = downsample2(gauss5x5_reflect(src)) ----
// one 32x32 down tile per block (64x64 src region + halo), z in [0,96):
// z<48 -> image A channel z, else image B channel z-48.
__global__ __launch_bounds__(256) void down_kernel(
    const float* __restrict__ src_a, const float* __restrict__ src_b,
    float* __restrict__ dst_a, float* __restrict__ dst_b, int H)
{
  const int W = H, H2 = H >> 1, W2 = W >> 1;
  const int bx = blockIdx.x, by = blockIdx.y;
  const int z = blockIdx.z;
  const int ch = (z >= NCH) ? z - NCH : z;
  const float* src = ((z >= NCH) ? src_b : src_a) + (size_t)ch * H * W;
  float* dst = ((z >= NCH) ? dst_b : dst_a) + (size_t)ch * H2 * W2;
  const int tid = threadIdx.x;

  __shared__ __align__(16) float s_in[67][72];   // 19.3 KB
  __shared__ __align__(16) float s_h[67][32];    //  8.6 KB

  const int rb = 64 * by - 2;                    // first needed src row
  const int S0 = max(0, 64 * bx - 4);            // staged col0 (4-aligned)

  // stage 67 rows x 18 float4 groups (row-reflect; col clamp, W%4==0 so
  // clamped slots are never read)
  for (int t = tid; t < 67 * 18; t += 256) {
    int r = t / 18, c4 = t - 18 * r;
    int gr = refl(rb + r, H);
    int gb = min(S0 + 4 * c4, W - 4);
    *reinterpret_cast<float4*>(&s_in[r][4 * c4]) =
        *reinterpret_cast<const float4*>(src + (size_t)gr * W + gb);
  }
  __syncthreads();

  // horizontal gauss: 67 rows x 32 down cols
  const bool cedge = (bx == 0) || (64 * bx + 64 >= W);
  for (int t = tid; t < 67 * 32; t += 256) {
    int r = t >> 5, d = t & 31;
    const float* row = s_in[r];
    int m = 2 * (32 * bx + d);
    float v;
    if (cedge) {
      v = row[refl(m - 2, W) - S0] + 4.f * row[refl(m - 1, W) - S0]
        + 6.f * row[m - S0] + 4.f * row[refl(m + 1, W) - S0]
        + row[refl(m + 2, W) - S0];
    } else {
      const float* p = row + (m - 2 - S0);
      v = p[0] + 4.f * p[1] + 6.f * p[2] + 4.f * p[3] + p[4];
    }
    s_h[r][d] = v;
  }
  __syncthreads();

  // vertical gauss + write: 32 rows x 8 float4 groups = 256 threads
  {
    int r = tid >> 3, g = tid & 7;
    float4 h0 = *reinterpret_cast<const float4*>(&s_h[2 * r][4 * g]);
    float4 h1 = *reinterpret_cast<const float4*>(&s_h[2 * r + 1][4 * g]);
    float4 h2 = *reinterpret_cast<const float4*>(&s_h[2 * r + 2][4 * g]);
    float4 h3 = *reinterpret_cast<const float4*>(&s_h[2 * r + 3][4 * g]);
    float4 h4 = *reinterpret_cast<const float4*>(&s_h[2 * r + 4][4 * g]);
    float4 o;
    o.x = (h0.x + h4.x + 6.f * h2.x + 4.f * (h1.x + h3.x)) * (1.f / 256.f);
    o.y = (h0.y + h4.y + 6.f * h2.y + 4.f * (h1.y + h3.y)) * (1.f / 256.f);
    o.z = (h0.z + h4.z + 6.f * h2.z + 4.f * (h1.z + h3.z)) * (1.f / 256.f);
    o.w = (h0.w + h4.w + 6.f * h2.w + 4.f * (h1.w + h3.w)) * (1.f / 256.f);
    *reinterpret_cast<float4*>(dst + (size_t)(32 * by + r) * W2 + 32 * bx + 4 * g) = o;
  }
}

// ---------------- merged loss kernel: all 3 levels in one launch ----------
__global__ __launch_bounds__(256) void loss_kernel(
    const float* __restrict__ in, const float* __restrict__ tg,
    const float* __restrict__ d0i, const float* __restrict__ d0t,
    const float* __restrict__ d1i, const float* __restrict__ d1t,
    const float* __restrict__ d2i, const float* __restrict__ d2t,
    double* __restrict__ partials)
{
  // decode (lvl, by, bx) from linear tile index 0..394
  int tb = blockIdx.x;
  int lvl, bx, by;
  if (tb < 289) { lvl = 0; by = tb / 17; bx = tb - 17 * by; }
  else if (tb < 370) { int u = tb - 289; lvl = 1; by = u / 9; bx = u - 9 * by; }
  else { int u = tb - 370; lvl = 2; by = u / 5; bx = u - 5 * by; }

  const int H = 512 >> lvl, W = H, HO = H + 2, H2 = H >> 1, W2 = W >> 1;
  const int n = blockIdx.z;
  const float* cb0 = (lvl == 0) ? in : (lvl == 1) ? d0i : d1i;
  const float* cb1 = (lvl == 0) ? tg : (lvl == 1) ? d0t : d1t;
  const float* db0 = (lvl == 0) ? d0i : (lvl == 1) ? d1i : d2i;
  const float* db1 = (lvl == 0) ? d0t : (lvl == 1) ? d1t : d2t;
  const float* curp[2] = {cb0 + (size_t)n * H * W, cb1 + (size_t)n * H * W};
  const float* dwp[2] = {db0 + (size_t)n * H2 * W2, db1 + (size_t)n * H2 * W2};
  const float scale = 1.f / (float)(NCH * HO * HO);

  const int x0 = bx * 32, y0 = by * 32;
  const int tid = threadIdx.x;

  __shared__ __align__(16) float s_diff[2][36][48];   // 13.8 KB
  __shared__ __align__(16) float s_tmp[2][36][24];    //  6.9 KB
  __shared__ __align__(16) float s_down[2][20][24];   //  3.8 KB

  const bool fast = (x0 >= 12) && (x0 + 52 <= W) && (y0 >= 6) && (y0 + 37 <= H);

  const int y_end = min(HO, y0 + 32), x_end = min(HO, x0 + 32);
  int rlo = max(0, y0 - 2);
  if (y_end > H) rlo = min(rlo, 2 * H - 1 - y_end);
  int clo = max(0, x0 - 2);
  if (x_end > W) clo = min(clo, 2 * W - 1 - x_end);
  const int nrows = min(H, y_end) - rlo;
  const int ncols = min(W, x_end) - clo;

  const int dr0 = fast ? (y0 >> 1) - 2 : (max(0, rlo - 2) >> 1);
  const int du0 = fast ? (x0 >> 1) - 4 : (max(0, clo - 2) >> 1);

  // ---- phase A': fill s_diff (cur window) + s_down (precomputed down) ----
  if (fast) {
    const int cbase = x0 - 8;     // s_diff col c <-> cur col x0-8+c (4-aligned)
    const int rbase = y0 - 2;     // s_diff row l <-> cur row y0-2+l
#pragma unroll
    for (int t = tid; t < 864; t += 256) {        // 2 img * 36 rows * 12 groups
      int img = t >= 432; int j = t - (img ? 432 : 0);
      int l = j / 12, c4 = j - 12 * l;
      *reinterpret_cast<float4*>(&s_diff[img][l][4 * c4]) =
          *reinterpret_cast<const float4*>(curp[img] + (size_t)(rbase + l) * W + cbase + 4 * c4);
    }
    if (tid < 240) {                              // 2 img * 20 rows * 6 groups
      int img = tid >= 120; int j = tid - (img ? 120 : 0);
      int k = j / 6, c4 = j - 6 * k;
      *reinterpret_cast<float4*>(&s_down[img][k][4 * c4]) =
          *reinterpret_cast<const float4*>(dwp[img] + (size_t)(dr0 + k) * W2 + du0 + 4 * c4);
    }
  } else {
    for (int t = tid; t < 2448; t += 256) {       // 2 * 34 * 36 diff window
      int img = t >= 1224; int j = t - (img ? 1224 : 0);
      int l = j / 36, c = j - 36 * l;
      if (l < nrows && c < ncols)
        s_diff[img][l][c] = curp[img][(size_t)(rlo + l) * W + clo + c];
    }
    for (int t = tid; t < 960; t += 256) {        // 2 * 20 * 24 down window
      int img = t >= 480; int j = t - (img ? 480 : 0);
      int k = j / 24, c = j - 24 * k;
      s_down[img][k][c] =
          dwp[img][(size_t)min(dr0 + k, H2 - 1) * W2 + min(du0 + c, W2 - 1)];
    }
  }
  __syncthreads();

  // ---- phase D: vertical up-pass -> s_tmp ----
  if (fast) {
    for (int t = tid; t < 432; t += 256) {
      int img = t / 216, j = t - 216 * img;
      int l = j / 6, c4 = j - 6 * l;
      int rr = (l + (l & 1)) >> 1;
      float4 a = *reinterpret_cast<const float4*>(&s_down[img][rr][4 * c4]);
      float4 b = *reinterpret_cast<const float4*>(&s_down[img][rr + 1][4 * c4]);
      float4 o;
      if (l & 1) {
        o.x = 0.5f * (a.x + b.x);
        o.y = 0.5f * (a.y + b.y);
        o.z = 0.5f * (a.z + b.z);
        o.w = 0.5f * (a.w + b.w);
      } else {
        float4 cc = *reinterpret_cast<const float4*>(&s_down[img][rr + 2][4 * c4]);
        o.x = 0.125f * (a.x + cc.x) + 0.75f * b.x;
        o.y = 0.125f * (a.y + cc.y) + 0.75f * b.y;
        o.z = 0.125f * (a.z + cc.z) + 0.75f * b.z;
        o.w = 0.125f * (a.w + cc.w) + 0.75f * b.w;
      }
      *reinterpret_cast<float4*>(&s_tmp[img][l][4 * c4]) = o;
    }
  } else {
    for (int t = tid; t < 2 * 34 * 24; t += 256) {
      int img = t / 816, j = t - 816 * img;
      int l = j / 24, du = j - 24 * l;
      int p = min(rlo + l, H - 1);
      int ur = min(du, W2 - 1 - du0);
      int par = p & 1;
      int f = p - 2 + par;
      int t0 = (refl(f, H) >> 1) - dr0;
      int t1 = (refl(f + 2, H) >> 1) - dr0;
      int t2 = (refl(f + 4, H) >> 1) - dr0;
      float w0v = par ? 0.5f : 0.125f;
      float w1v = par ? 0.5f : 0.75f;
      float w2v = par ? 0.0f : 0.125f;
      s_tmp[img][l][du] = w0v * s_down[img][t0][ur] + w1v * s_down[img][t1][ur]
                        + w2v * s_down[img][t2][ur];
    }
  }
  __syncthreads();

  // ---- phase E: horizontal up + diff in place over s_diff ----
  if (fast) {
    for (int t = tid; t < 720; t += 256) {
      int img = t / 360, j = t - 360 * img;
      int l = j / 10, c4 = j - 10 * l;
      float4 c = *reinterpret_cast<const float4*>(&s_diff[img][l][4 * c4 + 4]);
      const float* st = s_tmp[img][l];
      float Tm1 = st[2 * c4 + 1], T0 = st[2 * c4 + 2], T1 = st[2 * c4 + 3], T2 = st[2 * c4 + 4];
      float4 d;
      d.x = c.x - (0.125f * (Tm1 + T1) + 0.75f * T0);
      d.y = c.y - 0.5f * (T0 + T1);
      d.z = c.z - (0.125f * (T0 + T2) + 0.75f * T1);
      d.w = c.w - 0.5f * (T1 + T2);
      *reinterpret_cast<float4*>(&s_diff[img][l][4 * c4 + 4]) = d;
    }
  } else {
    for (int t = tid; t < 2448; t += 256) {
      int img = t / 1224, j = t - 1224 * img;
      int l = j / 36, cc = j - 36 * l;
      if (l < nrows && cc < ncols) {
        int q = clo + cc;
        int par = q & 1;
        int f = q - 2 + par;
        int tA = (refl(f, W) >> 1) - du0;
        int tB = (refl(f + 2, W) >> 1) - du0;
        int tC = (refl(f + 4, W) >> 1) - du0;
        float w0v = par ? 0.5f : 0.125f;
        float w1v = par ? 0.5f : 0.75f;
        float w2v = par ? 0.0f : 0.125f;
        float up = w0v * s_tmp[img][l][tA] + w1v * s_tmp[img][l][tB]
                 + w2v * s_tmp[img][l][tC];
        s_diff[img][l][cc] -= up;
      }
    }
  }
  __syncthreads();

  // ---- phase F: 3x3 |gx|+|gy| miniloss, |in - tg| ----
  float val = 0.f;
  if (fast) {
    const int tx = tid & 7, ty = tid >> 3;
    float ab[2][4];
#pragma unroll
    for (int img = 0; img < 2; ++img) {
      float a[3][6];
#pragma unroll
      for (int r = 0; r < 3; ++r) {
        const float* row = s_diff[img][ty + r];
        float4 M = *reinterpret_cast<const float4*>(&row[4 * tx + 4]);
        float4 R = *reinterpret_cast<const float4*>(&row[4 * tx + 8]);
        a[r][0] = M.z; a[r][1] = M.w; a[r][2] = R.x;
        a[r][3] = R.y; a[r][4] = R.z; a[r][5] = R.w;
      }
#pragma unroll
      for (int jj = 0; jj < 4; ++jj) {
        float tA = a[0][jj] - a[0][jj + 2];
        float tB = a[1][jj] - a[1][jj + 2];
        float tC = a[2][jj] - a[2][jj + 2];
        float gx = 2.f * (tA + tC) + 4.f * tB;
        float SA = 2.f * (a[0][jj] + a[0][jj + 2]) + 4.f * a[0][jj + 1];
        float SC = 2.f * (a[2][jj] + a[2][jj + 2]) + 4.f * a[2][jj + 1];
        ab[img][jj] = fabsf(gx) + fabsf(SA - SC);
      }
    }
#pragma unroll
    for (int jj = 0; jj < 4; ++jj) val += fabsf(ab[0][jj] - ab[1][jj]);
  } else {
    const int tx = tid & 31, tg8 = tid >> 5;
    const int xx = x0 + tx;
    if (xx < x_end) {
      const int cj0 = refl(xx - 2, W) - clo;
      const int cj1 = refl(xx - 1, W) - clo;
      const int cj2 = refl(xx, W) - clo;
      for (int k = 0; k < 4; ++k) {
        int yy = y0 + 4 * tg8 + k;
        if (yy >= y_end) break;
        int ri0 = refl(yy - 2, H) - rlo;
        int ri1 = refl(yy - 1, H) - rlo;
        int ri2 = refl(yy, H) - rlo;
        float ab2[2];
#pragma unroll
        for (int img = 0; img < 2; ++img) {
          float d00 = s_diff[img][ri0][cj0], d01 = s_diff[img][ri0][cj1], d02 = s_diff[img][ri0][cj2];
          float d10 = s_diff[img][ri1][cj0],                               d12 = s_diff[img][ri1][cj2];
          float d20 = s_diff[img][ri2][cj0], d21 = s_diff[img][ri2][cj1], d22 = s_diff[img][ri2][cj2];
          float gx = 2.f * (d00 - d02) + 4.f * (d10 - d12) + 2.f * (d20 - d22);
          float gy = 2.f * d00 + 4.f * d01 + 2.f * d02 - 2.f * d20 - 4.f * d21 - 2.f * d22;
          ab2[img] = fabsf(gx) + fabsf(gy);
        }
        val += fabsf(ab2[0] - ab2[1]);
      }
    }
  }
  val *= scale;

  // ---- reduction -> per-block partial slot ----
#pragma unroll
  for (int off = 32; off > 0; off >>= 1) val += __shfl_down(val, off, 64);
  __shared__ float wpart[4];
  if ((tid & 63) == 0) wpart[tid >> 6] = val;
  __syncthreads();
  if (tid == 0) {
    double s = (double)wpart[0] + (double)wpart[1] + (double)wpart[2] + (double)wpart[3];
    int lin = blockIdx.z * 395 + blockIdx.x;
    partials[lin] = s;
  }
}

__global__ __launch_bounds__(1024) void finalize_kernel(
    const double* __restrict__ partials, int N, float* __restrict__ out)
{
  double s = 0.0;
  for (int i = threadIdx.x; i < N; i += 1024) s += partials[i];
#pragma unroll
  for (int off = 32; off > 0; off >>= 1)
    s += __shfl_down(s, off, 64);
  __shared__ double wp[16];
  if ((threadIdx.x & 63) == 0) wp[threadIdx.x >> 6] = s;
  __syncthreads();
  if (threadIdx.x == 0) {
    double t = 0.0;
#pragma unroll
    for (int i = 0; i < 16; ++i) t += wp[i];
    out[0] = (float)t;
  }
}

extern "C" void kernel_launch(void* const* d_in, const int* in_sizes, int n_in,
                              void* d_out, int out_size, void* d_ws, size_t ws_size,
                              hipStream_t stream) {
  const float* in = (const float*)d_in[0];
  const float* tg = (const float*)d_in[1];
  float* out = (float*)d_out;

  const int NPART = 18960;   // 48 * (289 + 81 + 25)
  double* partials = (double*)d_ws;
  float* base = (float*)((char*)d_ws + (size_t)NPART * sizeof(double));
  const size_t s0 = (size_t)NCH * 256 * 256;
  const size_t s1 = (size_t)NCH * 128 * 128;
  const size_t s2 = (size_t)NCH * 64 * 64;
  float* d0i = base;
  float* d0t = d0i + s0;
  float* d1i = d0t + s0;
  float* d1t = d1i + s1;
  float* d2i = d1t + s1;
  float* d2t = d2i + s2;

  // pyramid of gauss-downsamples (memory-bound, small)
  down_kernel<<<dim3(8, 8, 2 * NCH), dim3(256), 0, stream>>>(in, tg, d0i, d0t, 512);
  down_kernel<<<dim3(4, 4, 2 * NCH), dim3(256), 0, stream>>>(d0i, d0t, d1i, d1t, 256);
  down_kernel<<<dim3(2, 2, 2 * NCH), dim3(256), 0, stream>>>(d1i, d1t, d2i, d2t, 128);

  // all three loss levels in one balanced launch
  loss_kernel<<<dim3(395, 1, NCH), dim3(256), 0, stream>>>(
      in, tg, d0i, d0t, d1i, d1t, d2i, d2t, partials);

  finalize_kernel<<<1, dim3(1024), 0, stream>>>(partials, NPART, out);
}

// Round 2
// 280.768 us; speedup vs baseline: 1.0579x; 1.0174x over previous
//
#include <hip/hip_runtime.h>

// Laplacian pyramid loss, 3 levels, B*C = 48 channels of 512x512 f32.
// R10: down_kernel rewritten register-space (shfl h-gauss fused into staging,
// s_in deleted, LDS 27.9KB -> 9.6KB, 5 -> 8 blocks/CU; reflect edges handled
// in-register with verbatim FP ordering). loss_kernel s_diff padded 48 -> 52
// floats to kill phase-E/F ds_read_b128 bank conflicts (8.2M conflict cycles).

#define NCH 48

__device__ __forceinline__ int refl(int p, int n) {
  return p < 0 ? -p : (p >= n ? 2 * n - 2 - p : p);
}

// ---------------- down kernel: dst = downsample2(gauss5x5_reflect(src)) ----
// one 32x32 down tile per block; z in [0,96): z<48 -> image A ch z, else B.
// Register-space h-gauss: thread loads float4 (4 src cols), shfl gives the
// neighbor halo, writes 2 h-gauss values to s_h. Column reflect needs only
// own-register specials (left m=0: z+4y+6x+4y+z; right m=W-2: x+4y+6z+4w+z).
__global__ __launch_bounds__(256) void down_kernel(
    const float* __restrict__ src_a, const float* __restrict__ src_b,
    float* __restrict__ dst_a, float* __restrict__ dst_b, int H)
{
  const int W = H, W2 = W >> 1;
  const int bx = blockIdx.x, by = blockIdx.y;
  const int z = blockIdx.z;
  const int ch = (z >= NCH) ? z - NCH : z;
  const float* src = ((z >= NCH) ? src_b : src_a) + (size_t)ch * H * W;
  float* dst = ((z >= NCH) ? dst_b : dst_a) + (size_t)ch * W2 * W2;
  const int tid = threadIdx.x;

  __shared__ __align__(16) float s_h[67][36];   // 9.6 KB (36 = pad vs 32)

  const int rb = 64 * by - 2;                   // first needed src row
  const int C0 = 64 * bx - 4;                   // group-0 col (may be <0)
  const bool lft = (bx == 0);
  const bool rgt = (64 * bx + 64 >= W);

  // stage + h-gauss: 67 rows x 18 float4 groups; compute groups 1..16
  for (int t = tid; t < 67 * 18; t += 256) {
    int r = t / 18, c4 = t - 18 * r;
    int gr = refl(rb + r, H);
    int gb = min(max(C0 + 4 * c4, 0), W - 4);
    float4 v = *reinterpret_cast<const float4*>(src + (size_t)gr * W + gb);
    float pz = __shfl_up(v.z, 1);
    float pw = __shfl_up(v.w, 1);
    float nx = __shfl_down(v.x, 1);
    if (c4 >= 1 && c4 <= 16) {
      // hb0: down col 32*bx + 2*c4 - 2  (m = C0 + 4*c4)
      float hb0;
      if (lft && c4 == 1)
        hb0 = v.z + 4.f * v.y + 6.f * v.x + 4.f * v.y + v.z;   // m=0 reflect
      else
        hb0 = pz + 4.f * pw + 6.f * v.x + 4.f * v.y + v.z;
      // hb1: down col 32*bx + 2*c4 - 1  (m = C0 + 4*c4 + 2)
      float nxe = (rgt && c4 == 16) ? v.z : nx;                // m=W-2 reflect
      float hb1 = v.x + 4.f * v.y + 6.f * v.z + 4.f * v.w + nxe;
      *reinterpret_cast<float2*>(&s_h[r][2 * c4 - 2]) = make_float2(hb0, hb1);
    }
  }
  __syncthreads();

  // vertical gauss + write: 32 rows x 8 float4 groups = 256 threads
  {
    int r = tid >> 3, g = tid & 7;
    float4 h0 = *reinterpret_cast<const float4*>(&s_h[2 * r][4 * g]);
    float4 h1 = *reinterpret_cast<const float4*>(&s_h[2 * r + 1][4 * g]);
    float4 h2 = *reinterpret_cast<const float4*>(&s_h[2 * r + 2][4 * g]);
    float4 h3 = *reinterpret_cast<const float4*>(&s_h[2 * r + 3][4 * g]);
    float4 h4 = *reinterpret_cast<const float4*>(&s_h[2 * r + 4][4 * g]);
    float4 o;
    o.x = (h0.x + h4.x + 6.f * h2.x + 4.f * (h1.x + h3.x)) * (1.f / 256.f);
    o.y = (h0.y + h4.y + 6.f * h2.y + 4.f * (h1.y + h3.y)) * (1.f / 256.f);
    o.z = (h0.z + h4.z + 6.f * h2.z + 4.f * (h1.z + h3.z)) * (1.f / 256.f);
    o.w = (h0.w + h4.w + 6.f * h2.w + 4.f * (h1.w + h3.w)) * (1.f / 256.f);
    *reinterpret_cast<float4*>(dst + (size_t)(32 * by + r) * W2 + 32 * bx + 4 * g) = o;
  }
}

// ---------------- merged loss kernel: all 3 levels in one launch ----------
__global__ __launch_bounds__(256) void loss_kernel(
    const float* __restrict__ in, const float* __restrict__ tg,
    const float* __restrict__ d0i, const float* __restrict__ d0t,
    const float* __restrict__ d1i, const float* __restrict__ d1t,
    const float* __restrict__ d2i, const float* __restrict__ d2t,
    double* __restrict__ partials)
{
  // decode (lvl, by, bx) from linear tile index 0..394
  int tb = blockIdx.x;
  int lvl, bx, by;
  if (tb < 289) { lvl = 0; by = tb / 17; bx = tb - 17 * by; }
  else if (tb < 370) { int u = tb - 289; lvl = 1; by = u / 9; bx = u - 9 * by; }
  else { int u = tb - 370; lvl = 2; by = u / 5; bx = u - 5 * by; }

  const int H = 512 >> lvl, W = H, HO = H + 2, H2 = H >> 1, W2 = W >> 1;
  const int n = blockIdx.z;
  const float* cb0 = (lvl == 0) ? in : (lvl == 1) ? d0i : d1i;
  const float* cb1 = (lvl == 0) ? tg : (lvl == 1) ? d0t : d1t;
  const float* db0 = (lvl == 0) ? d0i : (lvl == 1) ? d1i : d2i;
  const float* db1 = (lvl == 0) ? d0t : (lvl == 1) ? d1t : d2t;
  const float* curp[2] = {cb0 + (size_t)n * H * W, cb1 + (size_t)n * H * W};
  const float* dwp[2] = {db0 + (size_t)n * H2 * W2, db1 + (size_t)n * H2 * W2};
  const float scale = 1.f / (float)(NCH * HO * HO);

  const int x0 = bx * 32, y0 = by * 32;
  const int tid = threadIdx.x;

  __shared__ __align__(16) float s_diff[2][36][52];   // 15.0 KB (52 = pad)
  __shared__ __align__(16) float s_tmp[2][36][24];    //  6.9 KB
  __shared__ __align__(16) float s_down[2][20][24];   //  3.8 KB

  const bool fast = (x0 >= 12) && (x0 + 52 <= W) && (y0 >= 6) && (y0 + 37 <= H);

  const int y_end = min(HO, y0 + 32), x_end = min(HO, x0 + 32);
  int rlo = max(0, y0 - 2);
  if (y_end > H) rlo = min(rlo, 2 * H - 1 - y_end);
  int clo = max(0, x0 - 2);
  if (x_end > W) clo = min(clo, 2 * W - 1 - x_end);
  const int nrows = min(H, y_end) - rlo;
  const int ncols = min(W, x_end) - clo;

  const int dr0 = fast ? (y0 >> 1) - 2 : (max(0, rlo - 2) >> 1);
  const int du0 = fast ? (x0 >> 1) - 4 : (max(0, clo - 2) >> 1);

  // ---- phase A': fill s_diff (cur window) + s_down (precomputed down) ----
  if (fast) {
    const int cbase = x0 - 8;     // s_diff col c <-> cur col x0-8+c (4-aligned)
    const int rbase = y0 - 2;     // s_diff row l <-> cur row y0-2+l
#pragma unroll
    for (int t = tid; t < 864; t += 256) {        // 2 img * 36 rows * 12 groups
      int img = t >= 432; int j = t - (img ? 432 : 0);
      int l = j / 12, c4 = j - 12 * l;
      *reinterpret_cast<float4*>(&s_diff[img][l][4 * c4]) =
          *reinterpret_cast<const float4*>(curp[img] + (size_t)(rbase + l) * W + cbase + 4 * c4);
    }
    if (tid < 240) {                              // 2 img * 20 rows * 6 groups
      int img = tid >= 120; int j = tid - (img ? 120 : 0);
      int k = j / 6, c4 = j - 6 * k;
      *reinterpret_cast<float4*>(&s_down[img][k][4 * c4]) =
          *reinterpret_cast<const float4*>(dwp[img] + (size_t)(dr0 + k) * W2 + du0 + 4 * c4);
    }
  } else {
    for (int t = tid; t < 2448; t += 256) {       // 2 * 34 * 36 diff window
      int img = t >= 1224; int j = t - (img ? 1224 : 0);
      int l = j / 36, c = j - 36 * l;
      if (l < nrows && c < ncols)
        s_diff[img][l][c] = curp[img][(size_t)(rlo + l) * W + clo + c];
    }
    for (int t = tid; t < 960; t += 256) {        // 2 * 20 * 24 down window
      int img = t >= 480; int j = t - (img ? 480 : 0);
      int k = j / 24, c = j - 24 * k;
      s_down[img][k][c] =
          dwp[img][(size_t)min(dr0 + k, H2 - 1) * W2 + min(du0 + c, W2 - 1)];
    }
  }
  __syncthreads();

  // ---- phase D: vertical up-pass -> s_tmp ----
  if (fast) {
    for (int t = tid; t < 432; t += 256) {
      int img = t / 216, j = t - 216 * img;
      int l = j / 6, c4 = j - 6 * l;
      int rr = (l + (l & 1)) >> 1;
      float4 a = *reinterpret_cast<const float4*>(&s_down[img][rr][4 * c4]);
      float4 b = *reinterpret_cast<const float4*>(&s_down[img][rr + 1][4 * c4]);
      float4 o;
      if (l & 1) {
        o.x = 0.5f * (a.x + b.x);
        o.y = 0.5f * (a.y + b.y);
        o.z = 0.5f * (a.z + b.z);
        o.w = 0.5f * (a.w + b.w);
      } else {
        float4 cc = *reinterpret_cast<const float4*>(&s_down[img][rr + 2][4 * c4]);
        o.x = 0.125f * (a.x + cc.x) + 0.75f * b.x;
        o.y = 0.125f * (a.y + cc.y) + 0.75f * b.y;
        o.z = 0.125f * (a.z + cc.z) + 0.75f * b.z;
        o.w = 0.125f * (a.w + cc.w) + 0.75f * b.w;
      }
      *reinterpret_cast<float4*>(&s_tmp[img][l][4 * c4]) = o;
    }
  } else {
    for (int t = tid; t < 2 * 34 * 24; t += 256) {
      int img = t / 816, j = t - 816 * img;
      int l = j / 24, du = j - 24 * l;
      int p = min(rlo + l, H - 1);
      int ur = min(du, W2 - 1 - du0);
      int par = p & 1;
      int f = p - 2 + par;
      int t0 = (refl(f, H) >> 1) - dr0;
      int t1 = (refl(f + 2, H) >> 1) - dr0;
      int t2 = (refl(f + 4, H) >> 1) - dr0;
      float w0v = par ? 0.5f : 0.125f;
      float w1v = par ? 0.5f : 0.75f;
      float w2v = par ? 0.0f : 0.125f;
      s_tmp[img][l][du] = w0v * s_down[img][t0][ur] + w1v * s_down[img][t1][ur]
                        + w2v * s_down[img][t2][ur];
    }
  }
  __syncthreads();

  // ---- phase E: horizontal up + diff in place over s_diff ----
  if (fast) {
    for (int t = tid; t < 720; t += 256) {
      int img = t / 360, j = t - 360 * img;
      int l = j / 10, c4 = j - 10 * l;
      float4 c = *reinterpret_cast<const float4*>(&s_diff[img][l][4 * c4 + 4]);
      const float* st = s_tmp[img][l];
      float Tm1 = st[2 * c4 + 1], T0 = st[2 * c4 + 2], T1 = st[2 * c4 + 3], T2 = st[2 * c4 + 4];
      float4 d;
      d.x = c.x - (0.125f * (Tm1 + T1) + 0.75f * T0);
      d.y = c.y - 0.5f * (T0 + T1);
      d.z = c.z - (0.125f * (T0 + T2) + 0.75f * T1);
      d.w = c.w - 0.5f * (T1 + T2);
      *reinterpret_cast<float4*>(&s_diff[img][l][4 * c4 + 4]) = d;
    }
  } else {
    for (int t = tid; t < 2448; t += 256) {
      int img = t / 1224, j = t - 1224 * img;
      int l = j / 36, cc = j - 36 * l;
      if (l < nrows && cc < ncols) {
        int q = clo + cc;
        int par = q & 1;
        int f = q - 2 + par;
        int tA = (refl(f, W) >> 1) - du0;
        int tB = (refl(f + 2, W) >> 1) - du0;
        int tC = (refl(f + 4, W) >> 1) - du0;
        float w0v = par ? 0.5f : 0.125f;
        float w1v = par ? 0.5f : 0.75f;
        float w2v = par ? 0.0f : 0.125f;
        float up = w0v * s_tmp[img][l][tA] + w1v * s_tmp[img][l][tB]
                 + w2v * s_tmp[img][l][tC];
        s_diff[img][l][cc] -= up;
      }
    }
  }
  __syncthreads();

  // ---- phase F: 3x3 |gx|+|gy| miniloss, |in - tg| ----
  float val = 0.f;
  if (fast) {
    const int tx = tid & 7, ty = tid >> 3;
    float ab[2][4];
#pragma unroll
    for (int img = 0; img < 2; ++img) {
      float a[3][6];
#pragma unroll
      for (int r = 0; r < 3; ++r) {
        const float* row = s_diff[img][ty + r];
        float4 M = *reinterpret_cast<const float4*>(&row[4 * tx + 4]);
        float4 R = *reinterpret_cast<const float4*>(&row[4 * tx + 8]);
        a[r][0] = M.z; a[r][1] = M.w; a[r][2] = R.x;
        a[r][3] = R.y; a[r][4] = R.z; a[r][5] = R.w;
      }
#pragma unroll
      for (int jj = 0; jj < 4; ++jj) {
        float tA = a[0][jj] - a[0][jj + 2];
        float tB = a[1][jj] - a[1][jj + 2];
        float tC = a[2][jj] - a[2][jj + 2];
        float gx = 2.f * (tA + tC) + 4.f * tB;
        float SA = 2.f * (a[0][jj] + a[0][jj + 2]) + 4.f * a[0][jj + 1];
        float SC = 2.f * (a[2][jj] + a[2][jj + 2]) + 4.f * a[2][jj + 1];
        ab[img][jj] = fabsf(gx) + fabsf(SA - SC);
      }
    }
#pragma unroll
    for (int jj = 0; jj < 4; ++jj) val += fabsf(ab[0][jj] - ab[1][jj]);
  } else {
    const int tx = tid & 31, tg8 = tid >> 5;
    const int xx = x0 + tx;
    if (xx < x_end) {
      const int cj0 = refl(xx - 2, W) - clo;
      const int cj1 = refl(xx - 1, W) - clo;
      const int cj2 = refl(xx, W) - clo;
      for (int k = 0; k < 4; ++k) {
        int yy = y0 + 4 * tg8 + k;
        if (yy >= y_end) break;
        int ri0 = refl(yy - 2, H) - rlo;
        int ri1 = refl(yy - 1, H) - rlo;
        int ri2 = refl(yy, H) - rlo;
        float ab2[2];
#pragma unroll
        for (int img = 0; img < 2; ++img) {
          float d00 = s_diff[img][ri0][cj0], d01 = s_diff[img][ri0][cj1], d02 = s_diff[img][ri0][cj2];
          float d10 = s_diff[img][ri1][cj0],                               d12 = s_diff[img][ri1][cj2];
          float d20 = s_diff[img][ri2][cj0], d21 = s_diff[img][ri2][cj1], d22 = s_diff[img][ri2][cj2];
          float gx = 2.f * (d00 - d02) + 4.f * (d10 - d12) + 2.f * (d20 - d22);
          float gy = 2.f * d00 + 4.f * d01 + 2.f * d02 - 2.f * d20 - 4.f * d21 - 2.f * d22;
          ab2[img] = fabsf(gx) + fabsf(gy);
        }
        val += fabsf(ab2[0] - ab2[1]);
      }
    }
  }
  val *= scale;

  // ---- reduction -> per-block partial slot ----
#pragma unroll
  for (int off = 32; off > 0; off >>= 1) val += __shfl_down(val, off, 64);
  __shared__ float wpart[4];
  if ((tid & 63) == 0) wpart[tid >> 6] = val;
  __syncthreads();
  if (tid == 0) {
    double s = (double)wpart[0] + (double)wpart[1] + (double)wpart[2] + (double)wpart[3];
    int lin = blockIdx.z * 395 + blockIdx.x;
    partials[lin] = s;
  }
}

__global__ __launch_bounds__(1024) void finalize_kernel(
    const double* __restrict__ partials, int N, float* __restrict__ out)
{
  double s = 0.0;
  for (int i = threadIdx.x; i < N; i += 1024) s += partials[i];
#pragma unroll
  for (int off = 32; off > 0; off >>= 1)
    s += __shfl_down(s, off, 64);
  __shared__ double wp[16];
  if ((threadIdx.x & 63) == 0) wp[threadIdx.x >> 6] = s;
  __syncthreads();
  if (threadIdx.x == 0) {
    double t = 0.0;
#pragma unroll
    for (int i = 0; i < 16; ++i) t += wp[i];
    out[0] = (float)t;
  }
}

extern "C" void kernel_launch(void* const* d_in, const int* in_sizes, int n_in,
                              void* d_out, int out_size, void* d_ws, size_t ws_size,
                              hipStream_t stream) {
  const float* in = (const float*)d_in[0];
  const float* tg = (const float*)d_in[1];
  float* out = (float*)d_out;

  const int NPART = 18960;   // 48 * (289 + 81 + 25)
  double* partials = (double*)d_ws;
  float* base = (float*)((char*)d_ws + (size_t)NPART * sizeof(double));
  const size_t s0 = (size_t)NCH * 256 * 256;
  const size_t s1 = (size_t)NCH * 128 * 128;
  const size_t s2 = (size_t)NCH * 64 * 64;
  float* d0i = base;
  float* d0t = d0i + s0;
  float* d1i = d0t + s0;
  float* d1t = d1i + s1;
  float* d2i = d1t + s1;
  float* d2t = d2i + s2;

  // pyramid of gauss-downsamples (memory-bound, small)
  down_kernel<<<dim3(8, 8, 2 * NCH), dim3(256), 0, stream>>>(in, tg, d0i, d0t, 512);
  down_kernel<<<dim3(4, 4, 2 * NCH), dim3(256), 0, stream>>>(d0i, d0t, d1i, d1t, 256);
  down_kernel<<<dim3(2, 2, 2 * NCH), dim3(256), 0, stream>>>(d1i, d1t, d2i, d2t, 128);

  // all three loss levels in one balanced launch
  loss_kernel<<<dim3(395, 1, NCH), dim3(256), 0, stream>>>(
      in, tg, d0i, d0t, d1i, d1t, d2i, d2t, partials);

  finalize_kernel<<<1, dim3(1024), 0, stream>>>(partials, NPART, out);
}

// Round 3
// 279.279 us; speedup vs baseline: 1.0635x; 1.0053x over previous
//
#include <hip/hip_runtime.h>
#include <hip/hip_cooperative_groups.h>

namespace cg = cooperative_groups;

// Laplacian pyramid loss, 3 levels, B*C = 48 channels of 512x512 f32.
// R11: single persistent cooperative kernel. Phases D0 -> D1 -> D2 -> loss
// -> final reduce, separated by grid.sync() + __threadfence() (cross-XCD L2
// coherence). Down tile / loss tile bodies verbatim from R10/R9 (loss uses
// the stride-48 s_diff: 8.2M conflict version; the 52-pad was worse).
// 1280 blocks (5/CU guaranteed: launch_bounds(256,5), LDS 24.6KB).
// Fallback to the 5-kernel path if cooperative launch fails.

#define NCH 48

__device__ __forceinline__ int refl(int p, int n) {
  return p < 0 ? -p : (p >= n ? 2 * n - 2 - p : p);
}

// ---- down tile: one 32x32 down tile of dst = down2(gauss5_reflect(src)) ----
__device__ __forceinline__ void down_tile(
    const float* __restrict__ src, float* __restrict__ dst,
    int H, int bx, int by, float (*s_h)[36], int tid)
{
  const int W = H, W2 = W >> 1;
  const int rb = 64 * by - 2;                   // first needed src row
  const int C0 = 64 * bx - 4;                   // group-0 col (may be <0)
  const bool lft = (bx == 0);
  const bool rgt = (64 * bx + 64 >= W);

  // stage + h-gauss: 67 rows x 18 float4 groups; compute groups 1..16
  for (int t = tid; t < 67 * 18; t += 256) {
    int r = t / 18, c4 = t - 18 * r;
    int gr = refl(rb + r, H);
    int gb = min(max(C0 + 4 * c4, 0), W - 4);
    float4 v = *reinterpret_cast<const float4*>(src + (size_t)gr * W + gb);
    float pz = __shfl_up(v.z, 1);
    float pw = __shfl_up(v.w, 1);
    float nx = __shfl_down(v.x, 1);
    if (c4 >= 1 && c4 <= 16) {
      float hb0;
      if (lft && c4 == 1)
        hb0 = v.z + 4.f * v.y + 6.f * v.x + 4.f * v.y + v.z;   // m=0 reflect
      else
        hb0 = pz + 4.f * pw + 6.f * v.x + 4.f * v.y + v.z;
      float nxe = (rgt && c4 == 16) ? v.z : nx;                // m=W-2 reflect
      float hb1 = v.x + 4.f * v.y + 6.f * v.z + 4.f * v.w + nxe;
      *reinterpret_cast<float2*>(&s_h[r][2 * c4 - 2]) = make_float2(hb0, hb1);
    }
  }
  __syncthreads();

  // vertical gauss + write: 32 rows x 8 float4 groups = 256 threads
  {
    int r = tid >> 3, g = tid & 7;
    float4 h0 = *reinterpret_cast<const float4*>(&s_h[2 * r][4 * g]);
    float4 h1 = *reinterpret_cast<const float4*>(&s_h[2 * r + 1][4 * g]);
    float4 h2 = *reinterpret_cast<const float4*>(&s_h[2 * r + 2][4 * g]);
    float4 h3 = *reinterpret_cast<const float4*>(&s_h[2 * r + 3][4 * g]);
    float4 h4 = *reinterpret_cast<const float4*>(&s_h[2 * r + 4][4 * g]);
    float4 o;
    o.x = (h0.x + h4.x + 6.f * h2.x + 4.f * (h1.x + h3.x)) * (1.f / 256.f);
    o.y = (h0.y + h4.y + 6.f * h2.y + 4.f * (h1.y + h3.y)) * (1.f / 256.f);
    o.z = (h0.z + h4.z + 6.f * h2.z + 4.f * (h1.z + h3.z)) * (1.f / 256.f);
    o.w = (h0.w + h4.w + 6.f * h2.w + 4.f * (h1.w + h3.w)) * (1.f / 256.f);
    *reinterpret_cast<float4*>(dst + (size_t)(32 * by + r) * W2 + 32 * bx + 4 * g) = o;
  }
  __syncthreads();   // protect s_h before next unit reuses it
}

// ---- loss tile: one 32x32 output tile of one level; returns block partial --
__device__ __forceinline__ double loss_tile(
    const float* __restrict__ cur0, const float* __restrict__ cur1,
    const float* __restrict__ dw0, const float* __restrict__ dw1,
    int H, int bx, int by,
    float (*s_diff)[36][48], float (*s_tmp)[36][24], float (*s_down)[20][24],
    float* wpart, int tid)
{
  const int W = H, HO = H + 2, H2 = H >> 1, W2 = W >> 1;
  const float* curp[2] = {cur0, cur1};
  const float* dwp[2] = {dw0, dw1};
  const float scale = 1.f / (float)(NCH * HO * HO);

  const int x0 = bx * 32, y0 = by * 32;

  const bool fast = (x0 >= 12) && (x0 + 52 <= W) && (y0 >= 6) && (y0 + 37 <= H);

  const int y_end = min(HO, y0 + 32), x_end = min(HO, x0 + 32);
  int rlo = max(0, y0 - 2);
  if (y_end > H) rlo = min(rlo, 2 * H - 1 - y_end);
  int clo = max(0, x0 - 2);
  if (x_end > W) clo = min(clo, 2 * W - 1 - x_end);
  const int nrows = min(H, y_end) - rlo;
  const int ncols = min(W, x_end) - clo;

  const int dr0 = fast ? (y0 >> 1) - 2 : (max(0, rlo - 2) >> 1);
  const int du0 = fast ? (x0 >> 1) - 4 : (max(0, clo - 2) >> 1);

  // ---- phase A': fill s_diff (cur window) + s_down (precomputed down) ----
  if (fast) {
    const int cbase = x0 - 8;
    const int rbase = y0 - 2;
#pragma unroll
    for (int t = tid; t < 864; t += 256) {        // 2 img * 36 rows * 12 groups
      int img = t >= 432; int j = t - (img ? 432 : 0);
      int l = j / 12, c4 = j - 12 * l;
      *reinterpret_cast<float4*>(&s_diff[img][l][4 * c4]) =
          *reinterpret_cast<const float4*>(curp[img] + (size_t)(rbase + l) * W + cbase + 4 * c4);
    }
    if (tid < 240) {                              // 2 img * 20 rows * 6 groups
      int img = tid >= 120; int j = tid - (img ? 120 : 0);
      int k = j / 6, c4 = j - 6 * k;
      *reinterpret_cast<float4*>(&s_down[img][k][4 * c4]) =
          *reinterpret_cast<const float4*>(dwp[img] + (size_t)(dr0 + k) * W2 + du0 + 4 * c4);
    }
  } else {
    for (int t = tid; t < 2448; t += 256) {       // 2 * 34 * 36 diff window
      int img = t >= 1224; int j = t - (img ? 1224 : 0);
      int l = j / 36, c = j - 36 * l;
      if (l < nrows && c < ncols)
        s_diff[img][l][c] = curp[img][(size_t)(rlo + l) * W + clo + c];
    }
    for (int t = tid; t < 960; t += 256) {        // 2 * 20 * 24 down window
      int img = t >= 480; int j = t - (img ? 480 : 0);
      int k = j / 24, c = j - 24 * k;
      s_down[img][k][c] =
          dwp[img][(size_t)min(dr0 + k, H2 - 1) * W2 + min(du0 + c, W2 - 1)];
    }
  }
  __syncthreads();

  // ---- phase D: vertical up-pass -> s_tmp ----
  if (fast) {
    for (int t = tid; t < 432; t += 256) {
      int img = t / 216, j = t - 216 * img;
      int l = j / 6, c4 = j - 6 * l;
      int rr = (l + (l & 1)) >> 1;
      float4 a = *reinterpret_cast<const float4*>(&s_down[img][rr][4 * c4]);
      float4 b = *reinterpret_cast<const float4*>(&s_down[img][rr + 1][4 * c4]);
      float4 o;
      if (l & 1) {
        o.x = 0.5f * (a.x + b.x);
        o.y = 0.5f * (a.y + b.y);
        o.z = 0.5f * (a.z + b.z);
        o.w = 0.5f * (a.w + b.w);
      } else {
        float4 cc = *reinterpret_cast<const float4*>(&s_down[img][rr + 2][4 * c4]);
        o.x = 0.125f * (a.x + cc.x) + 0.75f * b.x;
        o.y = 0.125f * (a.y + cc.y) + 0.75f * b.y;
        o.z = 0.125f * (a.z + cc.z) + 0.75f * b.z;
        o.w = 0.125f * (a.w + cc.w) + 0.75f * b.w;
      }
      *reinterpret_cast<float4*>(&s_tmp[img][l][4 * c4]) = o;
    }
  } else {
    for (int t = tid; t < 2 * 34 * 24; t += 256) {
      int img = t / 816, j = t - 816 * img;
      int l = j / 24, du = j - 24 * l;
      int p = min(rlo + l, H - 1);
      int ur = min(du, W2 - 1 - du0);
      int par = p & 1;
      int f = p - 2 + par;
      int t0 = (refl(f, H) >> 1) - dr0;
      int t1 = (refl(f + 2, H) >> 1) - dr0;
      int t2 = (refl(f + 4, H) >> 1) - dr0;
      float w0v = par ? 0.5f : 0.125f;
      float w1v = par ? 0.5f : 0.75f;
      float w2v = par ? 0.0f : 0.125f;
      s_tmp[img][l][du] = w0v * s_down[img][t0][ur] + w1v * s_down[img][t1][ur]
                        + w2v * s_down[img][t2][ur];
    }
  }
  __syncthreads();

  // ---- phase E: horizontal up + diff in place over s_diff ----
  if (fast) {
    for (int t = tid; t < 720; t += 256) {
      int img = t / 360, j = t - 360 * img;
      int l = j / 10, c4 = j - 10 * l;
      float4 c = *reinterpret_cast<const float4*>(&s_diff[img][l][4 * c4 + 4]);
      const float* st = s_tmp[img][l];
      float Tm1 = st[2 * c4 + 1], T0 = st[2 * c4 + 2], T1 = st[2 * c4 + 3], T2 = st[2 * c4 + 4];
      float4 d;
      d.x = c.x - (0.125f * (Tm1 + T1) + 0.75f * T0);
      d.y = c.y - 0.5f * (T0 + T1);
      d.z = c.z - (0.125f * (T0 + T2) + 0.75f * T1);
      d.w = c.w - 0.5f * (T1 + T2);
      *reinterpret_cast<float4*>(&s_diff[img][l][4 * c4 + 4]) = d;
    }
  } else {
    for (int t = tid; t < 2448; t += 256) {
      int img = t / 1224, j = t - 1224 * img;
      int l = j / 36, cc = j - 36 * l;
      if (l < nrows && cc < ncols) {
        int q = clo + cc;
        int par = q & 1;
        int f = q - 2 + par;
        int tA = (refl(f, W) >> 1) - du0;
        int tB = (refl(f + 2, W) >> 1) - du0;
        int tC = (refl(f + 4, W) >> 1) - du0;
        float w0v = par ? 0.5f : 0.125f;
        float w1v = par ? 0.5f : 0.75f;
        float w2v = par ? 0.0f : 0.125f;
        float up = w0v * s_tmp[img][l][tA] + w1v * s_tmp[img][l][tB]
                 + w2v * s_tmp[img][l][tC];
        s_diff[img][l][cc] -= up;
      }
    }
  }
  __syncthreads();

  // ---- phase F: 3x3 |gx|+|gy| miniloss, |in - tg| ----
  float val = 0.f;
  if (fast) {
    const int tx = tid & 7, ty = tid >> 3;
    float ab[2][4];
#pragma unroll
    for (int img = 0; img < 2; ++img) {
      float a[3][6];
#pragma unroll
      for (int r = 0; r < 3; ++r) {
        const float* row = s_diff[img][ty + r];
        float4 M = *reinterpret_cast<const float4*>(&row[4 * tx + 4]);
        float4 R = *reinterpret_cast<const float4*>(&row[4 * tx + 8]);
        a[r][0] = M.z; a[r][1] = M.w; a[r][2] = R.x;
        a[r][3] = R.y; a[r][4] = R.z; a[r][5] = R.w;
      }
#pragma unroll
      for (int jj = 0; jj < 4; ++jj) {
        float tA = a[0][jj] - a[0][jj + 2];
        float tB = a[1][jj] - a[1][jj + 2];
        float tC = a[2][jj] - a[2][jj + 2];
        float gx = 2.f * (tA + tC) + 4.f * tB;
        float SA = 2.f * (a[0][jj] + a[0][jj + 2]) + 4.f * a[0][jj + 1];
        float SC = 2.f * (a[2][jj] + a[2][jj + 2]) + 4.f * a[2][jj + 1];
        ab[img][jj] = fabsf(gx) + fabsf(SA - SC);
      }
    }
#pragma unroll
    for (int jj = 0; jj < 4; ++jj) val += fabsf(ab[0][jj] - ab[1][jj]);
  } else {
    const int tx = tid & 31, tg8 = tid >> 5;
    const int xx = x0 + tx;
    if (xx < x_end) {
      const int cj0 = refl(xx - 2, W) - clo;
      const int cj1 = refl(xx - 1, W) - clo;
      const int cj2 = refl(xx, W) - clo;
      for (int k = 0; k < 4; ++k) {
        int yy = y0 + 4 * tg8 + k;
        if (yy >= y_end) break;
        int ri0 = refl(yy - 2, H) - rlo;
        int ri1 = refl(yy - 1, H) - rlo;
        int ri2 = refl(yy, H) - rlo;
        float ab2[2];
#pragma unroll
        for (int img = 0; img < 2; ++img) {
          float d00 = s_diff[img][ri0][cj0], d01 = s_diff[img][ri0][cj1], d02 = s_diff[img][ri0][cj2];
          float d10 = s_diff[img][ri1][cj0],                               d12 = s_diff[img][ri1][cj2];
          float d20 = s_diff[img][ri2][cj0], d21 = s_diff[img][ri2][cj1], d22 = s_diff[img][ri2][cj2];
          float gx = 2.f * (d00 - d02) + 4.f * (d10 - d12) + 2.f * (d20 - d22);
          float gy = 2.f * d00 + 4.f * d01 + 2.f * d02 - 2.f * d20 - 4.f * d21 - 2.f * d22;
          ab2[img] = fabsf(gx) + fabsf(gy);
        }
        val += fabsf(ab2[0] - ab2[1]);
      }
    }
  }
  val *= scale;

#pragma unroll
  for (int off = 32; off > 0; off >>= 1) val += __shfl_down(val, off, 64);
  if ((tid & 63) == 0) wpart[tid >> 6] = val;
  __syncthreads();
  double s = 0.0;
  if (tid == 0)
    s = (double)wpart[0] + (double)wpart[1] + (double)wpart[2] + (double)wpart[3];
  return s;
}

// ---------------- the single fused cooperative kernel ---------------------
__global__ __launch_bounds__(256, 5) void fused_all(
    const float* __restrict__ in, const float* __restrict__ tg,
    float* __restrict__ d0i, float* __restrict__ d0t,
    float* __restrict__ d1i, float* __restrict__ d1t,
    float* __restrict__ d2i, float* __restrict__ d2t,
    double* __restrict__ partials, float* __restrict__ out)
{
  cg::grid_group grid = cg::this_grid();
  const int tid = threadIdx.x;
  const int bid = blockIdx.x;
  const int nblk = gridDim.x;

  __shared__ __align__(16) float smem[6144];    // 24.6 KB, phase-aliased
  __shared__ float wpart[4];
  __shared__ double wpd[4];
  float (*s_h)[36] = reinterpret_cast<float (*)[36]>(smem);           // 67x36
  float (*s_diff)[36][48] = reinterpret_cast<float (*)[36][48]>(smem);
  float (*s_tmp)[36][24] = reinterpret_cast<float (*)[36][24]>(smem + 3456);
  float (*s_down)[20][24] = reinterpret_cast<float (*)[20][24]>(smem + 5184);

  // ---- phase D0: 8x8 tiles x 96 (img,ch) = 6144 units ----
  for (int u = bid; u < 6144; u += nblk) {
    int z = u >> 6, rm = u & 63, by = rm >> 3, bx = rm & 7;
    int ch = (z >= NCH) ? z - NCH : z;
    const float* src = ((z >= NCH) ? tg : in) + (size_t)ch * 512 * 512;
    float* dst = ((z >= NCH) ? d0t : d0i) + (size_t)ch * 256 * 256;
    down_tile(src, dst, 512, bx, by, s_h, tid);
  }
  __threadfence();
  grid.sync();

  // ---- phase D1: 4x4 x 96 = 1536 units ----
  for (int u = bid; u < 1536; u += nblk) {
    int z = u >> 4, rm = u & 15, by = rm >> 2, bx = rm & 3;
    int ch = (z >= NCH) ? z - NCH : z;
    const float* src = ((z >= NCH) ? d0t : d0i) + (size_t)ch * 256 * 256;
    float* dst = ((z >= NCH) ? d1t : d1i) + (size_t)ch * 128 * 128;
    down_tile(src, dst, 256, bx, by, s_h, tid);
  }
  __threadfence();
  grid.sync();

  // ---- phase D2: 2x2 x 96 = 384 units ----
  for (int u = bid; u < 384; u += nblk) {
    int z = u >> 2, rm = u & 3, by = rm >> 1, bx = rm & 1;
    int ch = (z >= NCH) ? z - NCH : z;
    const float* src = ((z >= NCH) ? d1t : d1i) + (size_t)ch * 128 * 128;
    float* dst = ((z >= NCH) ? d2t : d2i) + (size_t)ch * 64 * 64;
    down_tile(src, dst, 128, bx, by, s_h, tid);
  }
  __threadfence();
  grid.sync();

  // ---- loss phase: 395 tiles x 48 channels = 18960 units ----
  for (int u = bid; u < 18960; u += nblk) {
    int z = u / 395, tb = u - 395 * z;
    int lvl, bx, by;
    if (tb < 289) { lvl = 0; by = tb / 17; bx = tb - 17 * by; }
    else if (tb < 370) { int q = tb - 289; lvl = 1; by = q / 9; bx = q - 9 * by; }
    else { int q = tb - 370; lvl = 2; by = q / 5; bx = q - 5 * by; }
    const int H = 512 >> lvl;
    const float* cb0 = (lvl == 0) ? in : (lvl == 1) ? d0i : d1i;
    const float* cb1 = (lvl == 0) ? tg : (lvl == 1) ? d0t : d1t;
    const float* db0 = (lvl == 0) ? d0i : (lvl == 1) ? d1i : d2i;
    const float* db1 = (lvl == 0) ? d0t : (lvl == 1) ? d1t : d2t;
    size_t co = (size_t)z * H * H;
    size_t dof = (size_t)z * (H >> 1) * (H >> 1);
    double s = loss_tile(cb0 + co, cb1 + co, db0 + dof, db1 + dof,
                         H, bx, by, s_diff, s_tmp, s_down, wpart, tid);
    if (tid == 0) partials[u] = s;
    __syncthreads();
  }
  __threadfence();
  grid.sync();

  // ---- final reduce (block 0) ----
  if (bid == 0) {
    double s = 0.0;
    for (int i = tid; i < 18960; i += 256) s += partials[i];
#pragma unroll
    for (int off = 32; off > 0; off >>= 1) s += __shfl_down(s, off, 64);
    if ((tid & 63) == 0) wpd[tid >> 6] = s;
    __syncthreads();
    if (tid == 0) out[0] = (float)(wpd[0] + wpd[1] + wpd[2] + wpd[3]);
  }
}

// ---------------- fallback path (5 launches), verbatim R10/R9 -------------
__global__ __launch_bounds__(256) void down_kernel(
    const float* __restrict__ src_a, const float* __restrict__ src_b,
    float* __restrict__ dst_a, float* __restrict__ dst_b, int H)
{
  const int W = H, W2 = W >> 1;
  const int bx = blockIdx.x, by = blockIdx.y;
  const int z = blockIdx.z;
  const int ch = (z >= NCH) ? z - NCH : z;
  const float* src = ((z >= NCH) ? src_b : src_a) + (size_t)ch * H * W;
  float* dst = ((z >= NCH) ? dst_b : dst_a) + (size_t)ch * W2 * W2;
  __shared__ __align__(16) float s_h[67][36];
  down_tile(src, dst, H, bx, by, s_h, threadIdx.x);
}

__global__ __launch_bounds__(256) void loss_kernel(
    const float* __restrict__ in, const float* __restrict__ tg,
    const float* __restrict__ d0i, const float* __restrict__ d0t,
    const float* __restrict__ d1i, const float* __restrict__ d1t,
    const float* __restrict__ d2i, const float* __restrict__ d2t,
    double* __restrict__ partials)
{
  int tb = blockIdx.x;
  int lvl, bx, by;
  if (tb < 289) { lvl = 0; by = tb / 17; bx = tb - 17 * by; }
  else if (tb < 370) { int u = tb - 289; lvl = 1; by = u / 9; bx = u - 9 * by; }
  else { int u = tb - 370; lvl = 2; by = u / 5; bx = u - 5 * by; }
  const int H = 512 >> lvl;
  const int n = blockIdx.z;
  const float* cb0 = (lvl == 0) ? in : (lvl == 1) ? d0i : d1i;
  const float* cb1 = (lvl == 0) ? tg : (lvl == 1) ? d0t : d1t;
  const float* db0 = (lvl == 0) ? d0i : (lvl == 1) ? d1i : d2i;
  const float* db1 = (lvl == 0) ? d0t : (lvl == 1) ? d1t : d2t;
  size_t co = (size_t)n * H * H;
  size_t dof = (size_t)n * (H >> 1) * (H >> 1);
  __shared__ __align__(16) float s_diff[2][36][48];
  __shared__ __align__(16) float s_tmp[2][36][24];
  __shared__ __align__(16) float s_down[2][20][24];
  __shared__ float wpart[4];
  double s = loss_tile(cb0 + co, cb1 + co, db0 + dof, db1 + dof,
                       H, bx, by, s_diff, s_tmp, s_down, wpart, threadIdx.x);
  if (threadIdx.x == 0) partials[blockIdx.z * 395 + blockIdx.x] = s;
}

__global__ __launch_bounds__(1024) void finalize_kernel(
    const double* __restrict__ partials, int N, float* __restrict__ out)
{
  double s = 0.0;
  for (int i = threadIdx.x; i < N; i += 1024) s += partials[i];
#pragma unroll
  for (int off = 32; off > 0; off >>= 1)
    s += __shfl_down(s, off, 64);
  __shared__ double wp[16];
  if ((threadIdx.x & 63) == 0) wp[threadIdx.x >> 6] = s;
  __syncthreads();
  if (threadIdx.x == 0) {
    double t = 0.0;
#pragma unroll
    for (int i = 0; i < 16; ++i) t += wp[i];
    out[0] = (float)t;
  }
}

extern "C" void kernel_launch(void* const* d_in, const int* in_sizes, int n_in,
                              void* d_out, int out_size, void* d_ws, size_t ws_size,
                              hipStream_t stream) {
  const float* in = (const float*)d_in[0];
  const float* tg = (const float*)d_in[1];
  float* out = (float*)d_out;

  const int NPART = 18960;   // 48 * (289 + 81 + 25)
  double* partials = (double*)d_ws;
  float* base = (float*)((char*)d_ws + (size_t)NPART * sizeof(double));
  const size_t s0 = (size_t)NCH * 256 * 256;
  const size_t s1 = (size_t)NCH * 128 * 128;
  const size_t s2 = (size_t)NCH * 64 * 64;
  float* d0i = base;
  float* d0t = d0i + s0;
  float* d1i = d0t + s0;
  float* d1t = d1i + s1;
  float* d2i = d1t + s1;
  float* d2t = d2i + s2;

  static bool coop_ok = true;
  if (coop_ok) {
    const float* a0 = in; const float* a1 = tg;
    float* p0 = d0i; float* p1 = d0t; float* p2 = d1i; float* p3 = d1t;
    float* p4 = d2i; float* p5 = d2t;
    double* pp = partials; float* po = out;
    void* args[] = {&a0, &a1, &p0, &p1, &p2, &p3, &p4, &p5, &pp, &po};
    hipError_t e = hipLaunchCooperativeKernel(
        (const void*)fused_all, dim3(1280), dim3(256), args, 0, stream);
    if (e == hipSuccess) return;
    coop_ok = false;   // fall through to the 5-kernel path
  }

  down_kernel<<<dim3(8, 8, 2 * NCH), dim3(256), 0, stream>>>(in, tg, d0i, d0t, 512);
  down_kernel<<<dim3(4, 4, 2 * NCH), dim3(256), 0, stream>>>(d0i, d0t, d1i, d1t, 256);
  down_kernel<<<dim3(2, 2, 2 * NCH), dim3(256), 0, stream>>>(d1i, d1t, d2i, d2t, 128);
  loss_kernel<<<dim3(395, 1, NCH), dim3(256), 0, stream>>>(
      in, tg, d0i, d0t, d1i, d1t, d2i, d2t, partials);
  finalize_kernel<<<1, dim3(1024), 0, stream>>>(partials, NPART, out);
}

// Round 4
// 260.756 us; speedup vs baseline: 1.1391x; 1.0710x over previous
//
#include <hip/hip_runtime.h>

// Laplacian pyramid loss, 3 levels, B*C = 48 channels of 512x512 f32.
// R12: unified loss tile. All 395 tiles/channel run the vectorized fast-path
// phases D/E/F; reflection is folded entirely into STAGING (row/col reflect
// for s_diff, half-sample reflect dref for s_down; symmetric stencil weights
// + parity preservation make the fast formulas exact at virtual positions).
// Column-interior tiles (302/395) stage with float4 + row-reflect; only 93
// column-edge tiles use scalar gather staging. Phase F masks invalid outputs.
// Coop path removed (R3: net-zero). Down kernels verbatim R10.

#define NCH 48

__device__ __forceinline__ int refl(int p, int n) {
  return p < 0 ? -p : (p >= n ? 2 * n - 2 - p : p);
}
// down-space reflect: dref(j,n) == refl(2j, 2n) >> 1  (half-sample at right)
__device__ __forceinline__ int dref(int j, int n) {
  return j < 0 ? -j : (j >= n ? 2 * n - 1 - j : j);
}

// ---------------- down kernel: dst = downsample2(gauss5x5_reflect(src)) ----
__global__ __launch_bounds__(256) void down_kernel(
    const float* __restrict__ src_a, const float* __restrict__ src_b,
    float* __restrict__ dst_a, float* __restrict__ dst_b, int H)
{
  const int W = H, W2 = W >> 1;
  const int bx = blockIdx.x, by = blockIdx.y;
  const int z = blockIdx.z;
  const int ch = (z >= NCH) ? z - NCH : z;
  const float* src = ((z >= NCH) ? src_b : src_a) + (size_t)ch * H * W;
  float* dst = ((z >= NCH) ? dst_b : dst_a) + (size_t)ch * W2 * W2;
  const int tid = threadIdx.x;

  __shared__ __align__(16) float s_h[67][36];

  const int rb = 64 * by - 2;
  const int C0 = 64 * bx - 4;
  const bool lft = (bx == 0);
  const bool rgt = (64 * bx + 64 >= W);

  for (int t = tid; t < 67 * 18; t += 256) {
    int r = t / 18, c4 = t - 18 * r;
    int gr = refl(rb + r, H);
    int gb = min(max(C0 + 4 * c4, 0), W - 4);
    float4 v = *reinterpret_cast<const float4*>(src + (size_t)gr * W + gb);
    float pz = __shfl_up(v.z, 1);
    float pw = __shfl_up(v.w, 1);
    float nx = __shfl_down(v.x, 1);
    if (c4 >= 1 && c4 <= 16) {
      float hb0;
      if (lft && c4 == 1)
        hb0 = v.z + 4.f * v.y + 6.f * v.x + 4.f * v.y + v.z;   // m=0 reflect
      else
        hb0 = pz + 4.f * pw + 6.f * v.x + 4.f * v.y + v.z;
      float nxe = (rgt && c4 == 16) ? v.z : nx;                // m=W-2 reflect
      float hb1 = v.x + 4.f * v.y + 6.f * v.z + 4.f * v.w + nxe;
      *reinterpret_cast<float2*>(&s_h[r][2 * c4 - 2]) = make_float2(hb0, hb1);
    }
  }
  __syncthreads();

  {
    int r = tid >> 3, g = tid & 7;
    float4 h0 = *reinterpret_cast<const float4*>(&s_h[2 * r][4 * g]);
    float4 h1 = *reinterpret_cast<const float4*>(&s_h[2 * r + 1][4 * g]);
    float4 h2 = *reinterpret_cast<const float4*>(&s_h[2 * r + 2][4 * g]);
    float4 h3 = *reinterpret_cast<const float4*>(&s_h[2 * r + 3][4 * g]);
    float4 h4 = *reinterpret_cast<const float4*>(&s_h[2 * r + 4][4 * g]);
    float4 o;
    o.x = (h0.x + h4.x + 6.f * h2.x + 4.f * (h1.x + h3.x)) * (1.f / 256.f);
    o.y = (h0.y + h4.y + 6.f * h2.y + 4.f * (h1.y + h3.y)) * (1.f / 256.f);
    o.z = (h0.z + h4.z + 6.f * h2.z + 4.f * (h1.z + h3.z)) * (1.f / 256.f);
    o.w = (h0.w + h4.w + 6.f * h2.w + 4.f * (h1.w + h3.w)) * (1.f / 256.f);
    *reinterpret_cast<float4*>(dst + (size_t)(32 * by + r) * W2 + 32 * bx + 4 * g) = o;
  }
}

// ---------------- merged loss kernel: all 3 levels, unified fast tile ------
__global__ __launch_bounds__(256) void loss_kernel(
    const float* __restrict__ in, const float* __restrict__ tg,
    const float* __restrict__ d0i, const float* __restrict__ d0t,
    const float* __restrict__ d1i, const float* __restrict__ d1t,
    const float* __restrict__ d2i, const float* __restrict__ d2t,
    double* __restrict__ partials)
{
  int tb = blockIdx.x;
  int lvl, bx, by;
  if (tb < 289) { lvl = 0; by = tb / 17; bx = tb - 17 * by; }
  else if (tb < 370) { int u = tb - 289; lvl = 1; by = u / 9; bx = u - 9 * by; }
  else { int u = tb - 370; lvl = 2; by = u / 5; bx = u - 5 * by; }

  const int H = 512 >> lvl, W = H, HO = H + 2, H2 = H >> 1, W2 = W >> 1;
  const int n = blockIdx.z;
  const float* cb0 = (lvl == 0) ? in : (lvl == 1) ? d0i : d1i;
  const float* cb1 = (lvl == 0) ? tg : (lvl == 1) ? d0t : d1t;
  const float* db0 = (lvl == 0) ? d0i : (lvl == 1) ? d1i : d2i;
  const float* db1 = (lvl == 0) ? d0t : (lvl == 1) ? d1t : d2t;
  const float* curp[2] = {cb0 + (size_t)n * H * W, cb1 + (size_t)n * H * W};
  const float* dwp[2] = {db0 + (size_t)n * H2 * W2, db1 + (size_t)n * H2 * W2};
  const float scale = 1.f / (float)(NCH * HO * HO);

  const int x0 = bx * 32, y0 = by * 32;
  const int tid = threadIdx.x;

  __shared__ __align__(16) float s_diff[2][36][48];   // 13.8 KB
  __shared__ __align__(16) float s_tmp[2][36][24];    //  6.9 KB
  __shared__ __align__(16) float s_down[2][20][24];   //  3.8 KB

  // fixed fast-path geometry for ALL tiles
  const int cbase = x0 - 8, rbase = y0 - 2;
  const int dr0 = (y0 >> 1) - 2, du0 = (x0 >> 1) - 4;
  const bool vec = (x0 >= 32) && (x0 + 40 <= W);   // staged col span in-range
  const int x_end = min(HO, x0 + 32), y_end = min(HO, y0 + 32);

  // ---- phase A: stage s_diff (cur window) + s_down, reflect folded in ----
  if (vec) {
    for (int t = tid; t < 864; t += 256) {        // 2 img * 36 rows * 12 groups
      int img = t >= 432; int j = t - (img ? 432 : 0);
      int l = j / 12, c4 = j - 12 * l;
      int gr = refl(rbase + l, H);
      *reinterpret_cast<float4*>(&s_diff[img][l][4 * c4]) =
          *reinterpret_cast<const float4*>(curp[img] + (size_t)gr * W + cbase + 4 * c4);
    }
    if (tid < 240) {                              // 2 img * 20 rows * 6 groups
      int img = tid >= 120; int j = tid - (img ? 120 : 0);
      int k = j / 6, c4 = j - 6 * k;
      int gr = dref(dr0 + k, H2);
      *reinterpret_cast<float4*>(&s_down[img][k][4 * c4]) =
          *reinterpret_cast<const float4*>(dwp[img] + (size_t)gr * W2 + du0 + 4 * c4);
    }
  } else {
    for (int t = tid; t < 3456; t += 256) {       // 2 * 36 * 48 gather
      int img = t >= 1728; int j = t - (img ? 1728 : 0);
      int l = j / 48, c = j - 48 * l;
      int gr = refl(rbase + l, H), gc = refl(cbase + c, W);
      s_diff[img][l][c] = curp[img][(size_t)gr * W + gc];
    }
    for (int t = tid; t < 960; t += 256) {        // 2 * 20 * 24 gather
      int img = t >= 480; int j = t - (img ? 480 : 0);
      int k = j / 24, c = j - 24 * k;
      int gr = dref(dr0 + k, H2), gc = dref(du0 + c, W2);
      s_down[img][k][c] = dwp[img][(size_t)gr * W2 + gc];
    }
  }
  __syncthreads();

  // ---- phase D: vertical up-pass -> s_tmp (fast, all tiles) ----
  for (int t = tid; t < 432; t += 256) {
    int img = t / 216, j = t - 216 * img;
    int l = j / 6, c4 = j - 6 * l;
    int rr = (l + (l & 1)) >> 1;
    float4 a = *reinterpret_cast<const float4*>(&s_down[img][rr][4 * c4]);
    float4 b = *reinterpret_cast<const float4*>(&s_down[img][rr + 1][4 * c4]);
    float4 o;
    if (l & 1) {
      o.x = 0.5f * (a.x + b.x);
      o.y = 0.5f * (a.y + b.y);
      o.z = 0.5f * (a.z + b.z);
      o.w = 0.5f * (a.w + b.w);
    } else {
      float4 cc = *reinterpret_cast<const float4*>(&s_down[img][rr + 2][4 * c4]);
      o.x = 0.125f * (a.x + cc.x) + 0.75f * b.x;
      o.y = 0.125f * (a.y + cc.y) + 0.75f * b.y;
      o.z = 0.125f * (a.z + cc.z) + 0.75f * b.z;
      o.w = 0.125f * (a.w + cc.w) + 0.75f * b.w;
    }
    *reinterpret_cast<float4*>(&s_tmp[img][l][4 * c4]) = o;
  }
  __syncthreads();

  // ---- phase E: horizontal up + diff in place over s_diff (fast) ----
  for (int t = tid; t < 720; t += 256) {
    int img = t / 360, j = t - 360 * img;
    int l = j / 10, c4 = j - 10 * l;
    float4 c = *reinterpret_cast<const float4*>(&s_diff[img][l][4 * c4 + 4]);
    const float* st = s_tmp[img][l];
    float Tm1 = st[2 * c4 + 1], T0 = st[2 * c4 + 2], T1 = st[2 * c4 + 3], T2 = st[2 * c4 + 4];
    float4 d;
    d.x = c.x - (0.125f * (Tm1 + T1) + 0.75f * T0);
    d.y = c.y - 0.5f * (T0 + T1);
    d.z = c.z - (0.125f * (T0 + T2) + 0.75f * T1);
    d.w = c.w - 0.5f * (T1 + T2);
    *reinterpret_cast<float4*>(&s_diff[img][l][4 * c4 + 4]) = d;
  }
  __syncthreads();

  // ---- phase F: 3x3 |gx|+|gy| miniloss, |in - tg| (fast, masked) ----
  float val = 0.f;
  {
    const int tx = tid & 7, ty = tid >> 3;
    const int yy = y0 + ty;
    if (yy < y_end) {
      float ab[2][4];
#pragma unroll
      for (int img = 0; img < 2; ++img) {
        float a[3][6];
#pragma unroll
        for (int r = 0; r < 3; ++r) {
          const float* row = s_diff[img][ty + r];
          float4 M = *reinterpret_cast<const float4*>(&row[4 * tx + 4]);
          float4 R = *reinterpret_cast<const float4*>(&row[4 * tx + 8]);
          a[r][0] = M.z; a[r][1] = M.w; a[r][2] = R.x;
          a[r][3] = R.y; a[r][4] = R.z; a[r][5] = R.w;
        }
#pragma unroll
        for (int jj = 0; jj < 4; ++jj) {
          float tA = a[0][jj] - a[0][jj + 2];
          float tB = a[1][jj] - a[1][jj + 2];
          float tC = a[2][jj] - a[2][jj + 2];
          float gx = 2.f * (tA + tC) + 4.f * tB;
          float SA = 2.f * (a[0][jj] + a[0][jj + 2]) + 4.f * a[0][jj + 1];
          float SC = 2.f * (a[2][jj] + a[2][jj + 2]) + 4.f * a[2][jj + 1];
          ab[img][jj] = fabsf(gx) + fabsf(SA - SC);
        }
      }
      const int xb = x0 + 4 * tx;
#pragma unroll
      for (int jj = 0; jj < 4; ++jj)
        if (xb + jj < x_end) val += fabsf(ab[0][jj] - ab[1][jj]);
    }
  }
  val *= scale;

  // ---- reduction -> per-block partial slot ----
#pragma unroll
  for (int off = 32; off > 0; off >>= 1) val += __shfl_down(val, off, 64);
  __shared__ float wpart[4];
  if ((tid & 63) == 0) wpart[tid >> 6] = val;
  __syncthreads();
  if (tid == 0) {
    double s = (double)wpart[0] + (double)wpart[1] + (double)wpart[2] + (double)wpart[3];
    partials[blockIdx.z * 395 + blockIdx.x] = s;
  }
}

__global__ __launch_bounds__(1024) void finalize_kernel(
    const double* __restrict__ partials, int N, float* __restrict__ out)
{
  double s = 0.0;
  for (int i = threadIdx.x; i < N; i += 1024) s += partials[i];
#pragma unroll
  for (int off = 32; off > 0; off >>= 1)
    s += __shfl_down(s, off, 64);
  __shared__ double wp[16];
  if ((threadIdx.x & 63) == 0) wp[threadIdx.x >> 6] = s;
  __syncthreads();
  if (threadIdx.x == 0) {
    double t = 0.0;
#pragma unroll
    for (int i = 0; i < 16; ++i) t += wp[i];
    out[0] = (float)t;
  }
}

extern "C" void kernel_launch(void* const* d_in, const int* in_sizes, int n_in,
                              void* d_out, int out_size, void* d_ws, size_t ws_size,
                              hipStream_t stream) {
  const float* in = (const float*)d_in[0];
  const float* tg = (const float*)d_in[1];
  float* out = (float*)d_out;

  const int NPART = 18960;   // 48 * (289 + 81 + 25)
  double* partials = (double*)d_ws;
  float* base = (float*)((char*)d_ws + (size_t)NPART * sizeof(double));
  const size_t s0 = (size_t)NCH * 256 * 256;
  const size_t s1 = (size_t)NCH * 128 * 128;
  float* d0i = base;
  float* d0t = d0i + s0;
  float* d1i = d0t + s0;
  float* d1t = d1i + s1;
  float* d2i = d1t + s1;
  float* d2t = d2i + (size_t)NCH * 64 * 64;

  down_kernel<<<dim3(8, 8, 2 * NCH), dim3(256), 0, stream>>>(in, tg, d0i, d0t, 512);
  down_kernel<<<dim3(4, 4, 2 * NCH), dim3(256), 0, stream>>>(d0i, d0t, d1i, d1t, 256);
  down_kernel<<<dim3(2, 2, 2 * NCH), dim3(256), 0, stream>>>(d1i, d1t, d2i, d2t, 128);

  loss_kernel<<<dim3(395, 1, NCH), dim3(256), 0, stream>>>(
      in, tg, d0i, d0t, d1i, d1t, d2i, d2t, partials);

  finalize_kernel<<<1, dim3(1024), 0, stream>>>(partials, NPART, out);
}

// Round 5
// 256.599 us; speedup vs baseline: 1.1575x; 1.0162x over previous
//
#include <hip/hip_runtime.h>

// Laplacian pyramid loss, 3 levels, B*C = 48 channels of 512x512 f32.
// R13: R12 + LDS bank-conflict fix + phase-F trim.
//  - s_diff stride 48 -> 52 words: phase F's ds_read_b128 at stride 48 had
//    ty/ty+2 4-way bank aliasing (19.7M conflict cycles); 20*ty mod 32 at
//    stride 52 is uniform (8 words/bank, the b128 floor). LDS 26.1KB, still
//    6 blocks/CU.
//  - phase F: float2+float4 reads (6 words, was 8 via overlapping float4s);
//    separable |gx|/|gy| (same algebra, fewer VALU ops).
//  - down_kernel s_h stride 36 -> 34 (v-gauss read 4-way -> ~2-way).

#define NCH 48

__device__ __forceinline__ int refl(int p, int n) {
  return p < 0 ? -p : (p >= n ? 2 * n - 2 - p : p);
}
// down-space reflect: dref(j,n) == refl(2j, 2n) >> 1  (half-sample at right)
__device__ __forceinline__ int dref(int j, int n) {
  return j < 0 ? -j : (j >= n ? 2 * n - 1 - j : j);
}

// ---------------- down kernel: dst = downsample2(gauss5x5_reflect(src)) ----
__global__ __launch_bounds__(256) void down_kernel(
    const float* __restrict__ src_a, const float* __restrict__ src_b,
    float* __restrict__ dst_a, float* __restrict__ dst_b, int H)
{
  const int W = H, W2 = W >> 1;
  const int bx = blockIdx.x, by = blockIdx.y;
  const int z = blockIdx.z;
  const int ch = (z >= NCH) ? z - NCH : z;
  const float* src = ((z >= NCH) ? src_b : src_a) + (size_t)ch * H * W;
  float* dst = ((z >= NCH) ? dst_b : dst_a) + (size_t)ch * W2 * W2;
  const int tid = threadIdx.x;

  __shared__ __align__(16) float s_h[67][34];

  const int rb = 64 * by - 2;
  const int C0 = 64 * bx - 4;
  const bool lft = (bx == 0);
  const bool rgt = (64 * bx + 64 >= W);

  for (int t = tid; t < 67 * 18; t += 256) {
    int r = t / 18, c4 = t - 18 * r;
    int gr = refl(rb + r, H);
    int gb = min(max(C0 + 4 * c4, 0), W - 4);
    float4 v = *reinterpret_cast<const float4*>(src + (size_t)gr * W + gb);
    float pz = __shfl_up(v.z, 1);
    float pw = __shfl_up(v.w, 1);
    float nx = __shfl_down(v.x, 1);
    if (c4 >= 1 && c4 <= 16) {
      float hb0;
      if (lft && c4 == 1)
        hb0 = v.z + 4.f * v.y + 6.f * v.x + 4.f * v.y + v.z;   // m=0 reflect
      else
        hb0 = pz + 4.f * pw + 6.f * v.x + 4.f * v.y + v.z;
      float nxe = (rgt && c4 == 16) ? v.z : nx;                // m=W-2 reflect
      float hb1 = v.x + 4.f * v.y + 6.f * v.z + 4.f * v.w + nxe;
      *reinterpret_cast<float2*>(&s_h[r][2 * c4 - 2]) = make_float2(hb0, hb1);
    }
  }
  __syncthreads();

  {
    int r = tid >> 3, g = tid & 7;
    float4 h0 = *reinterpret_cast<const float4*>(&s_h[2 * r][4 * g]);
    float4 h1 = *reinterpret_cast<const float4*>(&s_h[2 * r + 1][4 * g]);
    float4 h2 = *reinterpret_cast<const float4*>(&s_h[2 * r + 2][4 * g]);
    float4 h3 = *reinterpret_cast<const float4*>(&s_h[2 * r + 3][4 * g]);
    float4 h4 = *reinterpret_cast<const float4*>(&s_h[2 * r + 4][4 * g]);
    float4 o;
    o.x = (h0.x + h4.x + 6.f * h2.x + 4.f * (h1.x + h3.x)) * (1.f / 256.f);
    o.y = (h0.y + h4.y + 6.f * h2.y + 4.f * (h1.y + h3.y)) * (1.f / 256.f);
    o.z = (h0.z + h4.z + 6.f * h2.z + 4.f * (h1.z + h3.z)) * (1.f / 256.f);
    o.w = (h0.w + h4.w + 6.f * h2.w + 4.f * (h1.w + h3.w)) * (1.f / 256.f);
    *reinterpret_cast<float4*>(dst + (size_t)(32 * by + r) * W2 + 32 * bx + 4 * g) = o;
  }
}

// ---------------- merged loss kernel: all 3 levels, unified fast tile ------
__global__ __launch_bounds__(256) void loss_kernel(
    const float* __restrict__ in, const float* __restrict__ tg,
    const float* __restrict__ d0i, const float* __restrict__ d0t,
    const float* __restrict__ d1i, const float* __restrict__ d1t,
    const float* __restrict__ d2i, const float* __restrict__ d2t,
    double* __restrict__ partials)
{
  int tb = blockIdx.x;
  int lvl, bx, by;
  if (tb < 289) { lvl = 0; by = tb / 17; bx = tb - 17 * by; }
  else if (tb < 370) { int u = tb - 289; lvl = 1; by = u / 9; bx = u - 9 * by; }
  else { int u = tb - 370; lvl = 2; by = u / 5; bx = u - 5 * by; }

  const int H = 512 >> lvl, W = H, HO = H + 2, H2 = H >> 1, W2 = W >> 1;
  const int n = blockIdx.z;
  const float* cb0 = (lvl == 0) ? in : (lvl == 1) ? d0i : d1i;
  const float* cb1 = (lvl == 0) ? tg : (lvl == 1) ? d0t : d1t;
  const float* db0 = (lvl == 0) ? d0i : (lvl == 1) ? d1i : d2i;
  const float* db1 = (lvl == 0) ? d0t : (lvl == 1) ? d1t : d2t;
  const float* curp[2] = {cb0 + (size_t)n * H * W, cb1 + (size_t)n * H * W};
  const float* dwp[2] = {db0 + (size_t)n * H2 * W2, db1 + (size_t)n * H2 * W2};
  const float scale = 1.f / (float)(NCH * HO * HO);

  const int x0 = bx * 32, y0 = by * 32;
  const int tid = threadIdx.x;

  __shared__ __align__(16) float s_diff[2][36][52];   // 15.0 KB (52: see hdr)
  __shared__ __align__(16) float s_tmp[2][36][24];    //  6.9 KB
  __shared__ __align__(16) float s_down[2][20][24];   //  3.8 KB

  // fixed fast-path geometry for ALL tiles
  const int cbase = x0 - 8, rbase = y0 - 2;
  const int dr0 = (y0 >> 1) - 2, du0 = (x0 >> 1) - 4;
  const bool vec = (x0 >= 32) && (x0 + 40 <= W);   // staged col span in-range
  const int x_end = min(HO, x0 + 32), y_end = min(HO, y0 + 32);

  // ---- phase A: stage s_diff (cur window) + s_down, reflect folded in ----
  if (vec) {
    for (int t = tid; t < 864; t += 256) {        // 2 img * 36 rows * 12 groups
      int img = t >= 432; int j = t - (img ? 432 : 0);
      int l = j / 12, c4 = j - 12 * l;
      int gr = refl(rbase + l, H);
      *reinterpret_cast<float4*>(&s_diff[img][l][4 * c4]) =
          *reinterpret_cast<const float4*>(curp[img] + (size_t)gr * W + cbase + 4 * c4);
    }
    if (tid < 240) {                              // 2 img * 20 rows * 6 groups
      int img = tid >= 120; int j = tid - (img ? 120 : 0);
      int k = j / 6, c4 = j - 6 * k;
      int gr = dref(dr0 + k, H2);
      *reinterpret_cast<float4*>(&s_down[img][k][4 * c4]) =
          *reinterpret_cast<const float4*>(dwp[img] + (size_t)gr * W2 + du0 + 4 * c4);
    }
  } else {
    for (int t = tid; t < 3456; t += 256) {       // 2 * 36 * 48 gather
      int img = t >= 1728; int j = t - (img ? 1728 : 0);
      int l = j / 48, c = j - 48 * l;
      int gr = refl(rbase + l, H), gc = refl(cbase + c, W);
      s_diff[img][l][c] = curp[img][(size_t)gr * W + gc];
    }
    for (int t = tid; t < 960; t += 256) {        // 2 * 20 * 24 gather
      int img = t >= 480; int j = t - (img ? 480 : 0);
      int k = j / 24, c = j - 24 * k;
      int gr = dref(dr0 + k, H2), gc = dref(du0 + c, W2);
      s_down[img][k][c] = dwp[img][(size_t)gr * W2 + gc];
    }
  }
  __syncthreads();

  // ---- phase D: vertical up-pass -> s_tmp (fast, all tiles) ----
  for (int t = tid; t < 432; t += 256) {
    int img = t / 216, j = t - 216 * img;
    int l = j / 6, c4 = j - 6 * l;
    int rr = (l + (l & 1)) >> 1;
    float4 a = *reinterpret_cast<const float4*>(&s_down[img][rr][4 * c4]);
    float4 b = *reinterpret_cast<const float4*>(&s_down[img][rr + 1][4 * c4]);
    float4 o;
    if (l & 1) {
      o.x = 0.5f * (a.x + b.x);
      o.y = 0.5f * (a.y + b.y);
      o.z = 0.5f * (a.z + b.z);
      o.w = 0.5f * (a.w + b.w);
    } else {
      float4 cc = *reinterpret_cast<const float4*>(&s_down[img][rr + 2][4 * c4]);
      o.x = 0.125f * (a.x + cc.x) + 0.75f * b.x;
      o.y = 0.125f * (a.y + cc.y) + 0.75f * b.y;
      o.z = 0.125f * (a.z + cc.z) + 0.75f * b.z;
      o.w = 0.125f * (a.w + cc.w) + 0.75f * b.w;
    }
    *reinterpret_cast<float4*>(&s_tmp[img][l][4 * c4]) = o;
  }
  __syncthreads();

  // ---- phase E: horizontal up + diff in place over s_diff (fast) ----
  for (int t = tid; t < 720; t += 256) {
    int img = t / 360, j = t - 360 * img;
    int l = j / 10, c4 = j - 10 * l;
    float4 c = *reinterpret_cast<const float4*>(&s_diff[img][l][4 * c4 + 4]);
    const float* st = s_tmp[img][l];
    float Tm1 = st[2 * c4 + 1], T0 = st[2 * c4 + 2], T1 = st[2 * c4 + 3], T2 = st[2 * c4 + 4];
    float4 d;
    d.x = c.x - (0.125f * (Tm1 + T1) + 0.75f * T0);
    d.y = c.y - 0.5f * (T0 + T1);
    d.z = c.z - (0.125f * (T0 + T2) + 0.75f * T1);
    d.w = c.w - 0.5f * (T1 + T2);
    *reinterpret_cast<float4*>(&s_diff[img][l][4 * c4 + 4]) = d;
  }
  __syncthreads();

  // ---- phase F: 3x3 |gx|+|gy| miniloss, |in - tg| (separable, masked) ----
  float val = 0.f;
  {
    const int tx = tid & 7, ty = tid >> 3;
    const int yy = y0 + ty;
    if (yy < y_end) {
      float ab[2][4];
#pragma unroll
      for (int img = 0; img < 2; ++img) {
        float a[3][6];
#pragma unroll
        for (int r = 0; r < 3; ++r) {
          const float* row = s_diff[img][ty + r];
          float2 L = *reinterpret_cast<const float2*>(&row[4 * tx + 6]);
          float4 R = *reinterpret_cast<const float4*>(&row[4 * tx + 8]);
          a[r][0] = L.x; a[r][1] = L.y; a[r][2] = R.x;
          a[r][3] = R.y; a[r][4] = R.z; a[r][5] = R.w;
        }
        float s[6], d[6], v[6];
#pragma unroll
        for (int k = 0; k < 6; ++k) {
          s[k] = a[0][k] + a[2][k];
          d[k] = a[0][k] - a[2][k];
          v[k] = 2.f * s[k] + 4.f * a[1][k];
        }
#pragma unroll
        for (int jj = 0; jj < 4; ++jj) {
          float gx = v[jj] - v[jj + 2];
          float u  = (d[jj] + d[jj + 2]) + 2.f * d[jj + 1];
          ab[img][jj] = fabsf(gx) + 2.f * fabsf(u);
        }
      }
      const int xb = x0 + 4 * tx;
#pragma unroll
      for (int jj = 0; jj < 4; ++jj)
        if (xb + jj < x_end) val += fabsf(ab[0][jj] - ab[1][jj]);
    }
  }
  val *= scale;

  // ---- reduction -> per-block partial slot ----
#pragma unroll
  for (int off = 32; off > 0; off >>= 1) val += __shfl_down(val, off, 64);
  __shared__ float wpart[4];
  if ((tid & 63) == 0) wpart[tid >> 6] = val;
  __syncthreads();
  if (tid == 0) {
    double s = (double)wpart[0] + (double)wpart[1] + (double)wpart[2] + (double)wpart[3];
    partials[blockIdx.z * 395 + blockIdx.x] = s;
  }
}

__global__ __launch_bounds__(1024) void finalize_kernel(
    const double* __restrict__ partials, int N, float* __restrict__ out)
{
  double s = 0.0;
  for (int i = threadIdx.x; i < N; i += 1024) s += partials[i];
#pragma unroll
  for (int off = 32; off > 0; off >>= 1)
    s += __shfl_down(s, off, 64);
  __shared__ double wp[16];
  if ((threadIdx.x & 63) == 0) wp[threadIdx.x >> 6] = s;
  __syncthreads();
  if (threadIdx.x == 0) {
    double t = 0.0;
#pragma unroll
    for (int i = 0; i < 16; ++i) t += wp[i];
    out[0] = (float)t;
  }
}

extern "C" void kernel_launch(void* const* d_in, const int* in_sizes, int n_in,
                              void* d_out, int out_size, void* d_ws, size_t ws_size,
                              hipStream_t stream) {
  const float* in = (const float*)d_in[0];
  const float* tg = (const float*)d_in[1];
  float* out = (float*)d_out;

  const int NPART = 18960;   // 48 * (289 + 81 + 25)
  double* partials = (double*)d_ws;
  float* base = (float*)((char*)d_ws + (size_t)NPART * sizeof(double));
  const size_t s0 = (size_t)NCH * 256 * 256;
  const size_t s1 = (size_t)NCH * 128 * 128;
  float* d0i = base;
  float* d0t = d0i + s0;
  float* d1i = d0t + s0;
  float* d1t = d1i + s1;
  float* d2i = d1t + s1;
  float* d2t = d2i + (size_t)NCH * 64 * 64;

  down_kernel<<<dim3(8, 8, 2 * NCH), dim3(256), 0, stream>>>(in, tg, d0i, d0t, 512);
  down_kernel<<<dim3(4, 4, 2 * NCH), dim3(256), 0, stream>>>(d0i, d0t, d1i, d1t, 256);
  down_kernel<<<dim3(2, 2, 2 * NCH), dim3(256), 0, stream>>>(d1i, d1t, d2i, d2t, 128);

  loss_kernel<<<dim3(395, 1, NCH), dim3(256), 0, stream>>>(
      in, tg, d0i, d0t, d1i, d1t, d2i, d2t, partials);

  finalize_kernel<<<1, dim3(1024), 0, stream>>>(partials, NPART, out);
}

// Round 6
// 230.961 us; speedup vs baseline: 1.2860x; 1.1110x over previous
//
#include <hip/hip_runtime.h>

// Laplacian pyramid loss, 3 levels, B*C = 48 channels of 512x512 f32.
// R14: R13 +
//  - vectorized edge staging: cbase/du0 and reflect pivots are all mult-of-4,
//    so every staged float4 group is purely forward (aligned float4 load) or
//    purely reflected (4 scalar loads, <=2 of 12 groups/row). Kills the
//    3456-elem scalar gather on the 93 edge tiles/channel.
//  - XCD-aware chunked swizzle (bijective: 18960=8*2370; down grids %8==0):
//    neighbor tiles of a channel share an XCD L2 -> halo re-reads hit L2.
//  - phase E s_tmp reads: 4 scalar (all-odd-bank, true 4-way) -> 2 aligned
//    float2 + 1 scalar.

#define NCH 48

__device__ __forceinline__ int refl(int p, int n) {
  return p < 0 ? -p : (p >= n ? 2 * n - 2 - p : p);
}
// down-space reflect: dref(j,n) == refl(2j, 2n) >> 1  (half-sample at right)
__device__ __forceinline__ int dref(int j, int n) {
  return j < 0 ? -j : (j >= n ? 2 * n - 1 - j : j);
}

// ---------------- down kernel: dst = downsample2(gauss5x5_reflect(src)) ----
// 1D grid, XCD-chunked swizzle. tl = log2(tiles_per_side).
__global__ __launch_bounds__(256) void down_kernel(
    const float* __restrict__ src_a, const float* __restrict__ src_b,
    float* __restrict__ dst_a, float* __restrict__ dst_b, int H, int tl)
{
  const int W = H, W2 = W >> 1;
  const int tps = 1 << tl, nt = tps * tps;
  const int total = 96 * nt;
  const int bid = blockIdx.x;
  const int s = (bid & 7) * (total >> 3) + (bid >> 3);   // XCD chunk
  const int z = s >> (2 * tl);
  const int rm = s & (nt - 1);
  const int by = rm >> tl, bx = rm & (tps - 1);

  const int ch = (z >= NCH) ? z - NCH : z;
  const float* src = ((z >= NCH) ? src_b : src_a) + (size_t)ch * H * W;
  float* dst = ((z >= NCH) ? dst_b : dst_a) + (size_t)ch * W2 * W2;
  const int tid = threadIdx.x;

  __shared__ __align__(16) float s_h[67][34];

  const int rb = 64 * by - 2;
  const int C0 = 64 * bx - 4;
  const bool lft = (bx == 0);
  const bool rgt = (64 * bx + 64 >= W);

  for (int t = tid; t < 67 * 18; t += 256) {
    int r = t / 18, c4 = t - 18 * r;
    int gr = refl(rb + r, H);
    int gb = min(max(C0 + 4 * c4, 0), W - 4);
    float4 v = *reinterpret_cast<const float4*>(src + (size_t)gr * W + gb);
    float pz = __shfl_up(v.z, 1);
    float pw = __shfl_up(v.w, 1);
    float nx = __shfl_down(v.x, 1);
    if (c4 >= 1 && c4 <= 16) {
      float hb0;
      if (lft && c4 == 1)
        hb0 = v.z + 4.f * v.y + 6.f * v.x + 4.f * v.y + v.z;   // m=0 reflect
      else
        hb0 = pz + 4.f * pw + 6.f * v.x + 4.f * v.y + v.z;
      float nxe = (rgt && c4 == 16) ? v.z : nx;                // m=W-2 reflect
      float hb1 = v.x + 4.f * v.y + 6.f * v.z + 4.f * v.w + nxe;
      *reinterpret_cast<float2*>(&s_h[r][2 * c4 - 2]) = make_float2(hb0, hb1);
    }
  }
  __syncthreads();

  {
    int r = tid >> 3, g = tid & 7;
    float4 h0 = *reinterpret_cast<const float4*>(&s_h[2 * r][4 * g]);
    float4 h1 = *reinterpret_cast<const float4*>(&s_h[2 * r + 1][4 * g]);
    float4 h2 = *reinterpret_cast<const float4*>(&s_h[2 * r + 2][4 * g]);
    float4 h3 = *reinterpret_cast<const float4*>(&s_h[2 * r + 3][4 * g]);
    float4 h4 = *reinterpret_cast<const float4*>(&s_h[2 * r + 4][4 * g]);
    float4 o;
    o.x = (h0.x + h4.x + 6.f * h2.x + 4.f * (h1.x + h3.x)) * (1.f / 256.f);
    o.y = (h0.y + h4.y + 6.f * h2.y + 4.f * (h1.y + h3.y)) * (1.f / 256.f);
    o.z = (h0.z + h4.z + 6.f * h2.z + 4.f * (h1.z + h3.z)) * (1.f / 256.f);
    o.w = (h0.w + h4.w + 6.f * h2.w + 4.f * (h1.w + h3.w)) * (1.f / 256.f);
    *reinterpret_cast<float4*>(dst + (size_t)(32 * by + r) * W2 + 32 * bx + 4 * g) = o;
  }
}

// ---------------- merged loss kernel: all 3 levels, unified fast tile ------
__global__ __launch_bounds__(256) void loss_kernel(
    const float* __restrict__ in, const float* __restrict__ tg,
    const float* __restrict__ d0i, const float* __restrict__ d0t,
    const float* __restrict__ d1i, const float* __restrict__ d1t,
    const float* __restrict__ d2i, const float* __restrict__ d2t,
    double* __restrict__ partials)
{
  // XCD-chunked bijective swizzle: 18960 = 8 * 2370
  const int bid = blockIdx.x;
  const int swz = (bid & 7) * 2370 + (bid >> 3);
  const int z = swz / 395;
  int tb = swz - 395 * z;
  int lvl, bx, by;
  if (tb < 289) { lvl = 0; by = tb / 17; bx = tb - 17 * by; }
  else if (tb < 370) { int u = tb - 289; lvl = 1; by = u / 9; bx = u - 9 * by; }
  else { int u = tb - 370; lvl = 2; by = u / 5; bx = u - 5 * by; }

  const int H = 512 >> lvl, W = H, HO = H + 2, H2 = H >> 1, W2 = W >> 1;
  const float* cb0 = (lvl == 0) ? in : (lvl == 1) ? d0i : d1i;
  const float* cb1 = (lvl == 0) ? tg : (lvl == 1) ? d0t : d1t;
  const float* db0 = (lvl == 0) ? d0i : (lvl == 1) ? d1i : d2i;
  const float* db1 = (lvl == 0) ? d0t : (lvl == 1) ? d1t : d2t;
  const float* curp[2] = {cb0 + (size_t)z * H * W, cb1 + (size_t)z * H * W};
  const float* dwp[2] = {db0 + (size_t)z * H2 * W2, db1 + (size_t)z * H2 * W2};
  const float scale = 1.f / (float)(NCH * HO * HO);

  const int x0 = bx * 32, y0 = by * 32;
  const int tid = threadIdx.x;

  __shared__ __align__(16) float s_diff[2][36][52];   // 15.0 KB
  __shared__ __align__(16) float s_tmp[2][36][24];    //  6.9 KB
  __shared__ __align__(16) float s_down[2][20][24];   //  3.8 KB

  // fixed fast-path geometry for ALL tiles
  const int cbase = x0 - 8, rbase = y0 - 2;
  const int dr0 = (y0 >> 1) - 2, du0 = (x0 >> 1) - 4;
  const bool vec = (x0 >= 32) && (x0 + 40 <= W);   // staged col span in-range
  const int x_end = min(HO, x0 + 32), y_end = min(HO, y0 + 32);

  // ---- phase A: stage s_diff (cur window) + s_down, reflect folded in ----
  if (vec) {
    for (int t = tid; t < 864; t += 256) {        // 2 img * 36 rows * 12 groups
      int img = t >= 432; int j = t - (img ? 432 : 0);
      int l = j / 12, c4 = j - 12 * l;
      int gr = refl(rbase + l, H);
      *reinterpret_cast<float4*>(&s_diff[img][l][4 * c4]) =
          *reinterpret_cast<const float4*>(curp[img] + (size_t)gr * W + cbase + 4 * c4);
    }
    if (tid < 240) {                              // 2 img * 20 rows * 6 groups
      int img = tid >= 120; int j = tid - (img ? 120 : 0);
      int k = j / 6, c4 = j - 6 * k;
      int gr = dref(dr0 + k, H2);
      *reinterpret_cast<float4*>(&s_down[img][k][4 * c4]) =
          *reinterpret_cast<const float4*>(dwp[img] + (size_t)gr * W2 + du0 + 4 * c4);
    }
  } else {
    // group-vectorized edge staging: every float4 group is purely forward
    // (aligned load) or reflected (scalar fallback; <=2 of 12 groups/row)
    for (int t = tid; t < 864; t += 256) {        // 2 img * 36 rows * 12 groups
      int img = t >= 432; int j = t - (img ? 432 : 0);
      int l = j / 12, g = j - 12 * l;
      int gr = refl(rbase + l, H);
      const float* rowp = curp[img] + (size_t)gr * W;
      int p0 = cbase + 4 * g;
      float4 v;
      if (p0 >= 0 && p0 + 3 < W) {
        v = *reinterpret_cast<const float4*>(rowp + p0);
      } else {
        v.x = rowp[refl(p0, W)];
        v.y = rowp[refl(p0 + 1, W)];
        v.z = rowp[refl(p0 + 2, W)];
        v.w = rowp[refl(p0 + 3, W)];
      }
      *reinterpret_cast<float4*>(&s_diff[img][l][4 * g]) = v;
    }
    if (tid < 240) {                              // 2 img * 20 rows * 6 groups
      int img = tid >= 120; int j = tid - (img ? 120 : 0);
      int k = j / 6, g = j - 6 * k;
      int gr = dref(dr0 + k, H2);
      const float* rowp = dwp[img] + (size_t)gr * W2;
      int p0 = du0 + 4 * g;
      float4 v;
      if (p0 >= 0 && p0 + 3 < W2) {
        v = *reinterpret_cast<const float4*>(rowp + p0);
      } else {
        v.x = rowp[dref(p0, W2)];
        v.y = rowp[dref(p0 + 1, W2)];
        v.z = rowp[dref(p0 + 2, W2)];
        v.w = rowp[dref(p0 + 3, W2)];
      }
      *reinterpret_cast<float4*>(&s_down[img][k][4 * g]) = v;
    }
  }
  __syncthreads();

  // ---- phase D: vertical up-pass -> s_tmp (fast, all tiles) ----
  for (int t = tid; t < 432; t += 256) {
    int img = t / 216, j = t - 216 * img;
    int l = j / 6, c4 = j - 6 * l;
    int rr = (l + (l & 1)) >> 1;
    float4 a = *reinterpret_cast<const float4*>(&s_down[img][rr][4 * c4]);
    float4 b = *reinterpret_cast<const float4*>(&s_down[img][rr + 1][4 * c4]);
    float4 o;
    if (l & 1) {
      o.x = 0.5f * (a.x + b.x);
      o.y = 0.5f * (a.y + b.y);
      o.z = 0.5f * (a.z + b.z);
      o.w = 0.5f * (a.w + b.w);
    } else {
      float4 cc = *reinterpret_cast<const float4*>(&s_down[img][rr + 2][4 * c4]);
      o.x = 0.125f * (a.x + cc.x) + 0.75f * b.x;
      o.y = 0.125f * (a.y + cc.y) + 0.75f * b.y;
      o.z = 0.125f * (a.z + cc.z) + 0.75f * b.z;
      o.w = 0.125f * (a.w + cc.w) + 0.75f * b.w;
    }
    *reinterpret_cast<float4*>(&s_tmp[img][l][4 * c4]) = o;
  }
  __syncthreads();

  // ---- phase E: horizontal up + diff in place over s_diff (fast) ----
  for (int t = tid; t < 720; t += 256) {
    int img = t / 360, j = t - 360 * img;
    int l = j / 10, c4 = j - 10 * l;
    float4 c = *reinterpret_cast<const float4*>(&s_diff[img][l][4 * c4 + 4]);
    const float* st = s_tmp[img][l];
    float2 A2 = *reinterpret_cast<const float2*>(&st[2 * c4]);
    float2 B2 = *reinterpret_cast<const float2*>(&st[2 * c4 + 2]);
    float T2 = st[2 * c4 + 4];
    float Tm1 = A2.y, T0 = B2.x, T1 = B2.y;
    float4 d;
    d.x = c.x - (0.125f * (Tm1 + T1) + 0.75f * T0);
    d.y = c.y - 0.5f * (T0 + T1);
    d.z = c.z - (0.125f * (T0 + T2) + 0.75f * T1);
    d.w = c.w - 0.5f * (T1 + T2);
    *reinterpret_cast<float4*>(&s_diff[img][l][4 * c4 + 4]) = d;
  }
  __syncthreads();

  // ---- phase F: 3x3 |gx|+|gy| miniloss, |in - tg| (separable, masked) ----
  float val = 0.f;
  {
    const int tx = tid & 7, ty = tid >> 3;
    const int yy = y0 + ty;
    if (yy < y_end) {
      float ab[2][4];
#pragma unroll
      for (int img = 0; img < 2; ++img) {
        float a[3][6];
#pragma unroll
        for (int r = 0; r < 3; ++r) {
          const float* row = s_diff[img][ty + r];
          float2 L = *reinterpret_cast<const float2*>(&row[4 * tx + 6]);
          float4 R = *reinterpret_cast<const float4*>(&row[4 * tx + 8]);
          a[r][0] = L.x; a[r][1] = L.y; a[r][2] = R.x;
          a[r][3] = R.y; a[r][4] = R.z; a[r][5] = R.w;
        }
        float s[6], d[6], v[6];
#pragma unroll
        for (int k = 0; k < 6; ++k) {
          s[k] = a[0][k] + a[2][k];
          d[k] = a[0][k] - a[2][k];
          v[k] = 2.f * s[k] + 4.f * a[1][k];
        }
#pragma unroll
        for (int jj = 0; jj < 4; ++jj) {
          float gx = v[jj] - v[jj + 2];
          float u  = (d[jj] + d[jj + 2]) + 2.f * d[jj + 1];
          ab[img][jj] = fabsf(gx) + 2.f * fabsf(u);
        }
      }
      const int xb = x0 + 4 * tx;
#pragma unroll
      for (int jj = 0; jj < 4; ++jj)
        if (xb + jj < x_end) val += fabsf(ab[0][jj] - ab[1][jj]);
    }
  }
  val *= scale;

  // ---- reduction -> per-block partial slot ----
#pragma unroll
  for (int off = 32; off > 0; off >>= 1) val += __shfl_down(val, off, 64);
  __shared__ float wpart[4];
  if ((tid & 63) == 0) wpart[tid >> 6] = val;
  __syncthreads();
  if (tid == 0) {
    double s = (double)wpart[0] + (double)wpart[1] + (double)wpart[2] + (double)wpart[3];
    partials[swz] = s;
  }
}

__global__ __launch_bounds__(1024) void finalize_kernel(
    const double* __restrict__ partials, int N, float* __restrict__ out)
{
  double s = 0.0;
  for (int i = threadIdx.x; i < N; i += 1024) s += partials[i];
#pragma unroll
  for (int off = 32; off > 0; off >>= 1)
    s += __shfl_down(s, off, 64);
  __shared__ double wp[16];
  if ((threadIdx.x & 63) == 0) wp[threadIdx.x >> 6] = s;
  __syncthreads();
  if (threadIdx.x == 0) {
    double t = 0.0;
#pragma unroll
    for (int i = 0; i < 16; ++i) t += wp[i];
    out[0] = (float)t;
  }
}

extern "C" void kernel_launch(void* const* d_in, const int* in_sizes, int n_in,
                              void* d_out, int out_size, void* d_ws, size_t ws_size,
                              hipStream_t stream) {
  const float* in = (const float*)d_in[0];
  const float* tg = (const float*)d_in[1];
  float* out = (float*)d_out;

  const int NPART = 18960;   // 48 * (289 + 81 + 25)
  double* partials = (double*)d_ws;
  float* base = (float*)((char*)d_ws + (size_t)NPART * sizeof(double));
  const size_t s0 = (size_t)NCH * 256 * 256;
  const size_t s1 = (size_t)NCH * 128 * 128;
  float* d0i = base;
  float* d0t = d0i + s0;
  float* d1i = d0t + s0;
  float* d1t = d1i + s1;
  float* d2i = d1t + s1;
  float* d2t = d2i + (size_t)NCH * 64 * 64;

  down_kernel<<<dim3(6144), dim3(256), 0, stream>>>(in, tg, d0i, d0t, 512, 3);
  down_kernel<<<dim3(1536), dim3(256), 0, stream>>>(d0i, d0t, d1i, d1t, 256, 2);
  down_kernel<<<dim3(384), dim3(256), 0, stream>>>(d1i, d1t, d2i, d2t, 128, 1);

  loss_kernel<<<dim3(18960), dim3(256), 0, stream>>>(
      in, tg, d0i, d0t, d1i, d1t, d2i, d2t, partials);

  finalize_kernel<<<1, dim3(1024), 0, stream>>>(partials, NPART, out);
}

// Round 7
// 228.548 us; speedup vs baseline: 1.2996x; 1.0106x over previous
//
#include <hip/hip_runtime.h>

// Laplacian pyramid loss, 3 levels, B*C = 48 channels of 512x512 f32.
// R15: R14 + phase-D fusion and LDS shrink.
//  - phase D (vertical up-pass -> s_tmp) fused into phase E: the 4 up-taps
//    are computed inline from s_down with the IDENTICAL expressions
//    (0.5f*(a+b) / 0.125f*(a+cc)+0.75f*b), so values are bit-identical.
//    Removes s_tmp (6.9 KB), one barrier, and the 432-item D loop.
//  - s_diff 48 -> 44 cols (stage 10 float4 groups = cur cols x0-4..x0+39;
//    needed span is x0-2..x0+33). Staging 864 -> 720 items.
//  - LDS 26.1 KB -> 16.6 KB: 6 -> 8 blocks/CU (full 32 waves/CU).

#define NCH 48

__device__ __forceinline__ int refl(int p, int n) {
  return p < 0 ? -p : (p >= n ? 2 * n - 2 - p : p);
}
// down-space reflect: dref(j,n) == refl(2j, 2n) >> 1  (half-sample at right)
__device__ __forceinline__ int dref(int j, int n) {
  return j < 0 ? -j : (j >= n ? 2 * n - 1 - j : j);
}

// ---------------- down kernel: dst = downsample2(gauss5x5_reflect(src)) ----
// 1D grid, XCD-chunked swizzle. tl = log2(tiles_per_side).
__global__ __launch_bounds__(256) void down_kernel(
    const float* __restrict__ src_a, const float* __restrict__ src_b,
    float* __restrict__ dst_a, float* __restrict__ dst_b, int H, int tl)
{
  const int W = H, W2 = W >> 1;
  const int tps = 1 << tl, nt = tps * tps;
  const int total = 96 * nt;
  const int bid = blockIdx.x;
  const int s = (bid & 7) * (total >> 3) + (bid >> 3);   // XCD chunk
  const int z = s >> (2 * tl);
  const int rm = s & (nt - 1);
  const int by = rm >> tl, bx = rm & (tps - 1);

  const int ch = (z >= NCH) ? z - NCH : z;
  const float* src = ((z >= NCH) ? src_b : src_a) + (size_t)ch * H * W;
  float* dst = ((z >= NCH) ? dst_b : dst_a) + (size_t)ch * W2 * W2;
  const int tid = threadIdx.x;

  __shared__ __align__(16) float s_h[67][34];

  const int rb = 64 * by - 2;
  const int C0 = 64 * bx - 4;
  const bool lft = (bx == 0);
  const bool rgt = (64 * bx + 64 >= W);

  for (int t = tid; t < 67 * 18; t += 256) {
    int r = t / 18, c4 = t - 18 * r;
    int gr = refl(rb + r, H);
    int gb = min(max(C0 + 4 * c4, 0), W - 4);
    float4 v = *reinterpret_cast<const float4*>(src + (size_t)gr * W + gb);
    float pz = __shfl_up(v.z, 1);
    float pw = __shfl_up(v.w, 1);
    float nx = __shfl_down(v.x, 1);
    if (c4 >= 1 && c4 <= 16) {
      float hb0;
      if (lft && c4 == 1)
        hb0 = v.z + 4.f * v.y + 6.f * v.x + 4.f * v.y + v.z;   // m=0 reflect
      else
        hb0 = pz + 4.f * pw + 6.f * v.x + 4.f * v.y + v.z;
      float nxe = (rgt && c4 == 16) ? v.z : nx;                // m=W-2 reflect
      float hb1 = v.x + 4.f * v.y + 6.f * v.z + 4.f * v.w + nxe;
      *reinterpret_cast<float2*>(&s_h[r][2 * c4 - 2]) = make_float2(hb0, hb1);
    }
  }
  __syncthreads();

  {
    int r = tid >> 3, g = tid & 7;
    float4 h0 = *reinterpret_cast<const float4*>(&s_h[2 * r][4 * g]);
    float4 h1 = *reinterpret_cast<const float4*>(&s_h[2 * r + 1][4 * g]);
    float4 h2 = *reinterpret_cast<const float4*>(&s_h[2 * r + 2][4 * g]);
    float4 h3 = *reinterpret_cast<const float4*>(&s_h[2 * r + 3][4 * g]);
    float4 h4 = *reinterpret_cast<const float4*>(&s_h[2 * r + 4][4 * g]);
    float4 o;
    o.x = (h0.x + h4.x + 6.f * h2.x + 4.f * (h1.x + h3.x)) * (1.f / 256.f);
    o.y = (h0.y + h4.y + 6.f * h2.y + 4.f * (h1.y + h3.y)) * (1.f / 256.f);
    o.z = (h0.z + h4.z + 6.f * h2.z + 4.f * (h1.z + h3.z)) * (1.f / 256.f);
    o.w = (h0.w + h4.w + 6.f * h2.w + 4.f * (h1.w + h3.w)) * (1.f / 256.f);
    *reinterpret_cast<float4*>(dst + (size_t)(32 * by + r) * W2 + 32 * bx + 4 * g) = o;
  }
}

// ---------------- merged loss kernel: all 3 levels, unified fast tile ------
__global__ __launch_bounds__(256) void loss_kernel(
    const float* __restrict__ in, const float* __restrict__ tg,
    const float* __restrict__ d0i, const float* __restrict__ d0t,
    const float* __restrict__ d1i, const float* __restrict__ d1t,
    const float* __restrict__ d2i, const float* __restrict__ d2t,
    double* __restrict__ partials)
{
  // XCD-chunked bijective swizzle: 18960 = 8 * 2370
  const int bid = blockIdx.x;
  const int swz = (bid & 7) * 2370 + (bid >> 3);
  const int z = swz / 395;
  int tb = swz - 395 * z;
  int lvl, bx, by;
  if (tb < 289) { lvl = 0; by = tb / 17; bx = tb - 17 * by; }
  else if (tb < 370) { int u = tb - 289; lvl = 1; by = u / 9; bx = u - 9 * by; }
  else { int u = tb - 370; lvl = 2; by = u / 5; bx = u - 5 * by; }

  const int H = 512 >> lvl, W = H, HO = H + 2, H2 = H >> 1, W2 = W >> 1;
  const float* cb0 = (lvl == 0) ? in : (lvl == 1) ? d0i : d1i;
  const float* cb1 = (lvl == 0) ? tg : (lvl == 1) ? d0t : d1t;
  const float* db0 = (lvl == 0) ? d0i : (lvl == 1) ? d1i : d2i;
  const float* db1 = (lvl == 0) ? d0t : (lvl == 1) ? d1t : d2t;
  const float* curp[2] = {cb0 + (size_t)z * H * W, cb1 + (size_t)z * H * W};
  const float* dwp[2] = {db0 + (size_t)z * H2 * W2, db1 + (size_t)z * H2 * W2};
  const float scale = 1.f / (float)(NCH * HO * HO);

  const int x0 = bx * 32, y0 = by * 32;
  const int tid = threadIdx.x;

  __shared__ __align__(16) float s_diff[2][36][44];   // 12.4 KB
  __shared__ __align__(16) float s_down[2][20][24];   //  3.8 KB

  // fixed fast-path geometry for ALL tiles.
  // s_diff col c <-> cur col (x0-4)+c  (10 staged float4 groups, cols 0..39)
  const int cbase = x0 - 4, rbase = y0 - 2;
  const int dr0 = (y0 >> 1) - 2, du0 = (x0 >> 1) - 4;
  const bool vec = (x0 >= 32) && (x0 + 40 <= W);
  const int x_end = min(HO, x0 + 32), y_end = min(HO, y0 + 32);

  // ---- phase A: stage s_diff (cur window) + s_down, reflect folded in ----
  if (vec) {
    for (int t = tid; t < 720; t += 256) {        // 2 img * 36 rows * 10 groups
      int img = t >= 360; int j = t - (img ? 360 : 0);
      int l = j / 10, g = j - 10 * l;
      int gr = refl(rbase + l, H);
      *reinterpret_cast<float4*>(&s_diff[img][l][4 * g]) =
          *reinterpret_cast<const float4*>(curp[img] + (size_t)gr * W + cbase + 4 * g);
    }
    if (tid < 240) {                              // 2 img * 20 rows * 6 groups
      int img = tid >= 120; int j = tid - (img ? 120 : 0);
      int k = j / 6, g = j - 6 * k;
      int gr = dref(dr0 + k, H2);
      *reinterpret_cast<float4*>(&s_down[img][k][4 * g]) =
          *reinterpret_cast<const float4*>(dwp[img] + (size_t)gr * W2 + du0 + 4 * g);
    }
  } else {
    // group-vectorized edge staging: each float4 group is purely forward
    // (aligned load) or reflected (scalar fallback)
    for (int t = tid; t < 720; t += 256) {
      int img = t >= 360; int j = t - (img ? 360 : 0);
      int l = j / 10, g = j - 10 * l;
      int gr = refl(rbase + l, H);
      const float* rowp = curp[img] + (size_t)gr * W;
      int p0 = cbase + 4 * g;
      float4 v;
      if (p0 >= 0 && p0 + 3 < W) {
        v = *reinterpret_cast<const float4*>(rowp + p0);
      } else {
        v.x = rowp[refl(p0, W)];
        v.y = rowp[refl(p0 + 1, W)];
        v.z = rowp[refl(p0 + 2, W)];
        v.w = rowp[refl(p0 + 3, W)];
      }
      *reinterpret_cast<float4*>(&s_diff[img][l][4 * g]) = v;
    }
    if (tid < 240) {
      int img = tid >= 120; int j = tid - (img ? 120 : 0);
      int k = j / 6, g = j - 6 * k;
      int gr = dref(dr0 + k, H2);
      const float* rowp = dwp[img] + (size_t)gr * W2;
      int p0 = du0 + 4 * g;
      float4 v;
      if (p0 >= 0 && p0 + 3 < W2) {
        v = *reinterpret_cast<const float4*>(rowp + p0);
      } else {
        v.x = rowp[dref(p0, W2)];
        v.y = rowp[dref(p0 + 1, W2)];
        v.z = rowp[dref(p0 + 2, W2)];
        v.w = rowp[dref(p0 + 3, W2)];
      }
      *reinterpret_cast<float4*>(&s_down[img][k][4 * g]) = v;
    }
  }
  __syncthreads();

  // ---- phase E (fused D): vertical+horizontal up + diff over s_diff ----
  // T[du] computed inline from s_down with D's exact expressions.
  for (int t = tid; t < 720; t += 256) {
    int img = t / 360, j = t - 360 * img;
    int l = j / 10, c4 = j - 10 * l;
    float4 c = *reinterpret_cast<const float4*>(&s_diff[img][l][4 * c4]);
    const int par = l & 1;
    const int rr = (l + par) >> 1;
    const int d0 = 2 * c4 + 1;                    // du of Tm1
    const float* rA = s_down[img][rr];
    const float* rB = s_down[img][rr + 1];
    float Tm1, T0, T1, T2;
    if (par) {
      Tm1 = 0.5f * (rA[d0] + rB[d0]);
      T0  = 0.5f * (rA[d0 + 1] + rB[d0 + 1]);
      T1  = 0.5f * (rA[d0 + 2] + rB[d0 + 2]);
      T2  = 0.5f * (rA[d0 + 3] + rB[d0 + 3]);
    } else {
      const float* rC = s_down[img][rr + 2];
      Tm1 = 0.125f * (rA[d0] + rC[d0]) + 0.75f * rB[d0];
      T0  = 0.125f * (rA[d0 + 1] + rC[d0 + 1]) + 0.75f * rB[d0 + 1];
      T1  = 0.125f * (rA[d0 + 2] + rC[d0 + 2]) + 0.75f * rB[d0 + 2];
      T2  = 0.125f * (rA[d0 + 3] + rC[d0 + 3]) + 0.75f * rB[d0 + 3];
    }
    float4 d;
    d.x = c.x - (0.125f * (Tm1 + T1) + 0.75f * T0);
    d.y = c.y - 0.5f * (T0 + T1);
    d.z = c.z - (0.125f * (T0 + T2) + 0.75f * T1);
    d.w = c.w - 0.5f * (T1 + T2);
    *reinterpret_cast<float4*>(&s_diff[img][l][4 * c4]) = d;
  }
  __syncthreads();

  // ---- phase F: 3x3 |gx|+|gy| miniloss, |in - tg| (separable, masked) ----
  float val = 0.f;
  {
    const int tx = tid & 7, ty = tid >> 3;
    const int yy = y0 + ty;
    if (yy < y_end) {
      float ab[2][4];
#pragma unroll
      for (int img = 0; img < 2; ++img) {
        float a[3][6];
#pragma unroll
        for (int r = 0; r < 3; ++r) {
          const float* row = s_diff[img][ty + r];
          float2 L = *reinterpret_cast<const float2*>(&row[4 * tx + 2]);
          float4 R = *reinterpret_cast<const float4*>(&row[4 * tx + 4]);
          a[r][0] = L.x; a[r][1] = L.y; a[r][2] = R.x;
          a[r][3] = R.y; a[r][4] = R.z; a[r][5] = R.w;
        }
        float s[6], d[6], v[6];
#pragma unroll
        for (int k = 0; k < 6; ++k) {
          s[k] = a[0][k] + a[2][k];
          d[k] = a[0][k] - a[2][k];
          v[k] = 2.f * s[k] + 4.f * a[1][k];
        }
#pragma unroll
        for (int jj = 0; jj < 4; ++jj) {
          float gx = v[jj] - v[jj + 2];
          float u  = (d[jj] + d[jj + 2]) + 2.f * d[jj + 1];
          ab[img][jj] = fabsf(gx) + 2.f * fabsf(u);
        }
      }
      const int xb = x0 + 4 * tx;
#pragma unroll
      for (int jj = 0; jj < 4; ++jj)
        if (xb + jj < x_end) val += fabsf(ab[0][jj] - ab[1][jj]);
    }
  }
  val *= scale;

  // ---- reduction -> per-block partial slot ----
#pragma unroll
  for (int off = 32; off > 0; off >>= 1) val += __shfl_down(val, off, 64);
  __shared__ float wpart[4];
  if ((tid & 63) == 0) wpart[tid >> 6] = val;
  __syncthreads();
  if (tid == 0) {
    double s = (double)wpart[0] + (double)wpart[1] + (double)wpart[2] + (double)wpart[3];
    partials[swz] = s;
  }
}

__global__ __launch_bounds__(1024) void finalize_kernel(
    const double* __restrict__ partials, int N, float* __restrict__ out)
{
  double s = 0.0;
  for (int i = threadIdx.x; i < N; i += 1024) s += partials[i];
#pragma unroll
  for (int off = 32; off > 0; off >>= 1)
    s += __shfl_down(s, off, 64);
  __shared__ double wp[16];
  if ((threadIdx.x & 63) == 0) wp[threadIdx.x >> 6] = s;
  __syncthreads();
  if (threadIdx.x == 0) {
    double t = 0.0;
#pragma unroll
    for (int i = 0; i < 16; ++i) t += wp[i];
    out[0] = (float)t;
  }
}

extern "C" void kernel_launch(void* const* d_in, const int* in_sizes, int n_in,
                              void* d_out, int out_size, void* d_ws, size_t ws_size,
                              hipStream_t stream) {
  const float* in = (const float*)d_in[0];
  const float* tg = (const float*)d_in[1];
  float* out = (float*)d_out;

  const int NPART = 18960;   // 48 * (289 + 81 + 25)
  double* partials = (double*)d_ws;
  float* base = (float*)((char*)d_ws + (size_t)NPART * sizeof(double));
  const size_t s0 = (size_t)NCH * 256 * 256;
  const size_t s1 = (size_t)NCH * 128 * 128;
  float* d0i = base;
  float* d0t = d0i + s0;
  float* d1i = d0t + s0;
  float* d1t = d1i + s1;
  float* d2i = d1t + s1;
  float* d2t = d2i + (size_t)NCH * 64 * 64;

  down_kernel<<<dim3(6144), dim3(256), 0, stream>>>(in, tg, d0i, d0t, 512, 3);
  down_kernel<<<dim3(1536), dim3(256), 0, stream>>>(d0i, d0t, d1i, d1t, 256, 2);
  down_kernel<<<dim3(384), dim3(256), 0, stream>>>(d1i, d1t, d2i, d2t, 128, 1);

  loss_kernel<<<dim3(18960), dim3(256), 0, stream>>>(
      in, tg, d0i, d0t, d1i, d1t, d2i, d2t, partials);

  finalize_kernel<<<1, dim3(1024), 0, stream>>>(partials, NPART, out);
}